// Round 8
// baseline (1448.588 us; speedup 1.0000x reference)
//
#include <hip/hip_runtime.h>
#include <hip/hip_bf16.h>
#include <type_traits>

#define NN 50000     // nodes per side (users == items == 50000)
#define NE 600000    // edges per relation
#define HF 256       // hidden features

typedef float f32x4 __attribute__((ext_vector_type(4)));
typedef _Float16 f16x8 __attribute__((ext_vector_type(8)));
typedef _Float16 f16x4 __attribute__((ext_vector_type(4)));

// ---------- fp32 -> fp16 convert, both inputs in one dispatch ----------
__global__ __launch_bounds__(256) void k_tofp16_2(const float* __restrict__ A,
                                                  const float* __restrict__ B,
                                                  _Float16* __restrict__ OA,
                                                  _Float16* __restrict__ OB, int n4) {
  int i = blockIdx.x * 256 + threadIdx.x;
  const float* X = (i < n4) ? A : B;
  _Float16* Y = (i < n4) ? OA : OB;
  int j = (i < n4) ? i : i - n4;
  if (j < n4) {
    float4 v = reinterpret_cast<const float4*>(X)[j];
    f16x4 o = {(_Float16)v.x, (_Float16)v.y, (_Float16)v.z, (_Float16)v.w};
    reinterpret_cast<f16x4*>(Y)[j] = o;
  }
}

// ---------- all 8 W[K][256] -> Wt[256][K] transposes in one dispatch ----------
struct TArgs {
  const float* W[8];
  _Float16* dst[8];
  int K[8];
  int cum[9];
};
__global__ __launch_bounds__(256) void k_transpose_all(TArgs t) {
  int idx = blockIdx.x * 256 + threadIdx.x;
#pragma unroll
  for (int s = 0; s < 8; ++s) {
    if (idx >= t.cum[s] && idx < t.cum[s + 1]) {
      int local = idx - t.cum[s];
      int K = t.K[s];
      int k = local >> 8;
      int n = local & 255;
      t.dst[s][(size_t)n * K + k] = (_Float16)t.W[s][local];
    }
  }
}

// ---------- all W.ar attn tables in one dispatch: out[(l*2+r)*1024 + k*4 + h] ----------
__global__ __launch_bounds__(256) void k_makeattn_all(
    const float* __restrict__ W1, const float* __restrict__ W2,
    const float* __restrict__ W3, const float* __restrict__ W4,
    const float* __restrict__ ar1, const float* __restrict__ ar2,
    const float* __restrict__ ar3, const float* __restrict__ ar4,
    float* __restrict__ out) {
  int idx = blockIdx.x * 256 + threadIdx.x;
  if (idx >= 8 * 256 * 4) return;
  int h = idx & 3;
  int k = (idx >> 2) & 255;
  int s = idx >> 10;  // l*2+r
  int l = s >> 1, r = s & 1;
  int K = (l == 0) ? 128 : 256;
  if (k >= K) return;
  const float* W = (l == 0 ? W1 : l == 1 ? W2 : l == 2 ? W3 : W4) + (size_t)r * K * 256;
  const float* a = (l == 0 ? ar1 : l == 1 ? ar2 : l == 2 ? ar3 : ar4) + r * 256 + h * 64;
  const float* wrow = W + (size_t)k * 256 + h * 64;
  float sum = 0.f;
#pragma unroll 8
  for (int d = 0; d < 64; ++d) sum += wrow[d] * a[d];
  out[s * 1024 + k * 4 + h] = sum;
}

// ---------- BN helpers ----------
__device__ __forceinline__ void bnparams8(const float* __restrict__ sums,
                                          const float* __restrict__ sqs,
                                          const float* __restrict__ g,
                                          const float* __restrict__ bt,
                                          int k, float* scale, float* shift) {
  const float invN = 1.0f / NN;
  float4 s0 = *reinterpret_cast<const float4*>(sums + k);
  float4 s1 = *reinterpret_cast<const float4*>(sums + k + 4);
  float4 q0 = *reinterpret_cast<const float4*>(sqs + k);
  float4 q1 = *reinterpret_cast<const float4*>(sqs + k + 4);
  float4 g0 = *reinterpret_cast<const float4*>(g + k);
  float4 g1 = *reinterpret_cast<const float4*>(g + k + 4);
  float4 b0 = *reinterpret_cast<const float4*>(bt + k);
  float4 b1 = *reinterpret_cast<const float4*>(bt + k + 4);
  float sa[8] = {s0.x, s0.y, s0.z, s0.w, s1.x, s1.y, s1.z, s1.w};
  float qa[8] = {q0.x, q0.y, q0.z, q0.w, q1.x, q1.y, q1.z, q1.w};
  float ga[8] = {g0.x, g0.y, g0.z, g0.w, g1.x, g1.y, g1.z, g1.w};
  float ba[8] = {b0.x, b0.y, b0.z, b0.w, b1.x, b1.y, b1.z, b1.w};
#pragma unroll
  for (int j = 0; j < 8; ++j) {
    float mu = sa[j] * invN;
    float var = qa[j] * invN - mu * mu;
    float rs = rsqrtf(var + 1e-5f) * ga[j];
    scale[j] = rs;
    shift[j] = ba[j] - mu * rs;
  }
}

__device__ __forceinline__ float actf(float v, int mode) {
  if (mode == 1) return v >= 0.f ? v : 0.01f * v;
  if (mode == 2) return tanhf(v);
  return v;
}

// ---------- GEMM pair with fused BN(+act) on A-load, el epilogue, er tail ----------
struct GArgs {
  const _Float16* A0; const _Float16* A1;     // raw inputs (pre-BN for mode>0)
  const _Float16* Wt0; const _Float16* Wt1;
  _Float16* Z0; _Float16* Z1;
  const float* al0; const float* al1;
  float* EL0; float* EL1;
  const float* war_s0; const float* war_s1;   // W.ar tables: side0 -> er1, side1 -> er0
  float* ER_s0; float* ER_s1;                 // side0 writes ER1, side1 writes ER0
  const float* su; const float* qu; const float* gu; const float* bu;  // side0 BN stats/params
  const float* si; const float* qi; const float* gi; const float* bi;  // side1
  int M, K, mode;                             // mode: 0 none, 1 leaky0.01, 2 tanh
};

__global__ __launch_bounds__(256) void k_gemm3(GArgs ga) {
  int mgrid = (ga.M + 63) / 64;
  int side = blockIdx.x >= mgrid;
  int bid = side ? blockIdx.x - mgrid : blockIdx.x;
  const _Float16* A = side ? ga.A1 : ga.A0;
  const _Float16* Wt = side ? ga.Wt1 : ga.Wt0;
  _Float16* Z = side ? ga.Z1 : ga.Z0;
  const float* al = side ? ga.al1 : ga.al0;
  float* EL = side ? ga.EL1 : ga.EL0;
  const float* war = side ? ga.war_s1 : ga.war_s0;
  float* ER = side ? ga.ER_s1 : ga.ER_s0;
  const float* sums = side ? ga.si : ga.su;
  const float* sqs = side ? ga.qi : ga.qu;
  const float* gg = side ? ga.gi : ga.gu;
  const float* bb = side ? ga.bi : ga.bu;
  const int K = ga.K, M = ga.M, mode = ga.mode;

  int wave = threadIdx.x >> 6;
  int lane = threadIdx.x & 63;
  int lr = lane & 15;   // fragment row (A) / col (B)
  int kg = lane >> 4;   // k-group: k = kg*8 + j
  int row0 = bid * 64;
  int col0 = wave * 64;
  f32x4 acc[4][4];
#pragma unroll
  for (int i = 0; i < 4; ++i)
#pragma unroll
    for (int j = 0; j < 4; ++j) acc[i][j] = (f32x4){0.f, 0.f, 0.f, 0.f};

  for (int k0 = 0; k0 < K; k0 += 32) {
    float scale[8], shift[8];
    if (mode) bnparams8(sums, sqs, gg, bb, k0 + kg * 8, scale, shift);
    f16x8 af[4], bfr[4];
#pragma unroll
    for (int mt = 0; mt < 4; ++mt) {
      int r = row0 + mt * 16 + lr;
      if (r >= M) r = M - 1;  // clamp loads; stores are guarded
      f16x8 raw = *reinterpret_cast<const f16x8*>(A + (size_t)r * K + k0 + kg * 8);
      if (mode) {
        f16x8 o;
#pragma unroll
        for (int j = 0; j < 8; ++j) {
          float v = (float)raw[j] * scale[j] + shift[j];
          o[j] = (_Float16)actf(v, mode);
        }
        af[mt] = o;
      } else {
        af[mt] = raw;
      }
    }
#pragma unroll
    for (int ct = 0; ct < 4; ++ct) {
      int c = col0 + ct * 16 + lr;
      bfr[ct] = *reinterpret_cast<const f16x8*>(Wt + (size_t)c * K + k0 + kg * 8);
    }
#pragma unroll
    for (int mt = 0; mt < 4; ++mt)
#pragma unroll
      for (int ct = 0; ct < 4; ++ct)
        acc[mt][ct] = __builtin_amdgcn_mfma_f32_16x16x32_f16(af[mt], bfr[ct], acc[mt][ct], 0, 0, 0);
  }
  // C/D layout: col = lane&15, row = (lane>>4)*4 + reg
#pragma unroll
  for (int mt = 0; mt < 4; ++mt) {
#pragma unroll
    for (int r = 0; r < 4; ++r) {
      int row = row0 + mt * 16 + kg * 4 + r;
      if (row < M) {
#pragma unroll
        for (int ct = 0; ct < 4; ++ct) {
          int col = col0 + ct * 16 + lr;
          Z[(size_t)row * HF + col] = (_Float16)acc[mt][ct][r];
        }
      }
    }
  }
  // fused el epilogue: el[row][h=wave] = sum_col z[row][col] * al[col]
  float al4[4];
#pragma unroll
  for (int ct = 0; ct < 4; ++ct) al4[ct] = al[wave * 64 + ct * 16 + lr];
#pragma unroll
  for (int mt = 0; mt < 4; ++mt) {
#pragma unroll
    for (int r = 0; r < 4; ++r) {
      float p = acc[mt][0][r] * al4[0] + acc[mt][1][r] * al4[1] +
                acc[mt][2][r] * al4[2] + acc[mt][3][r] * al4[3];
#pragma unroll
      for (int off = 1; off < 16; off <<= 1) p += __shfl_xor(p, off);
      int row = row0 + mt * 16 + kg * 4 + r;
      if (lr == 0 && row < M) EL[(size_t)row * 4 + wave] = p;
    }
  }
  // er tail: er_other[row][h] = BN(A[row]) . war[:,h]; thread = (row_local, quarter)
  {
    int rl = threadIdx.x >> 2;   // 0..63
    int q = threadIdx.x & 3;
    int row = row0 + rl;
    int rowc = row < M ? row : M - 1;
    int kq = q * (K >> 2);
    float p0 = 0.f, p1 = 0.f, p2 = 0.f, p3 = 0.f;
    for (int k = kq; k < kq + (K >> 2); k += 8) {
      f16x8 raw = *reinterpret_cast<const f16x8*>(A + (size_t)rowc * K + k);
      float va[8];
      if (mode) {
        float scale[8], shift[8];
        bnparams8(sums, sqs, gg, bb, k, scale, shift);
#pragma unroll
        for (int j = 0; j < 8; ++j) va[j] = actf((float)raw[j] * scale[j] + shift[j], mode);
      } else {
#pragma unroll
        for (int j = 0; j < 8; ++j) va[j] = (float)raw[j];
      }
#pragma unroll
      for (int j = 0; j < 8; ++j) {
        float4 wv = *reinterpret_cast<const float4*>(war + (k + j) * 4);
        p0 += va[j] * wv.x; p1 += va[j] * wv.y; p2 += va[j] * wv.z; p3 += va[j] * wv.w;
      }
    }
    p0 += __shfl_xor(p0, 1); p0 += __shfl_xor(p0, 2);
    p1 += __shfl_xor(p1, 1); p1 += __shfl_xor(p1, 2);
    p2 += __shfl_xor(p2, 1); p2 += __shfl_xor(p2, 2);
    p3 += __shfl_xor(p3, 1); p3 += __shfl_xor(p3, 2);
    if (q == 0 && row < M)
      *reinterpret_cast<float4*>(ER + (size_t)row * 4) = (float4){p0, p1, p2, p3};
  }
}

// ---------- CSR build (both relations per dispatch) ----------
__global__ __launch_bounds__(256) void k_hist2(const int* __restrict__ d0, const int* __restrict__ d1,
                                               int* __restrict__ c0, int* __restrict__ c1) {
  int t = blockIdx.x * 256 + threadIdx.x;
  if (t < NE) atomicAdd(&c0[d0[t]], 1);
  else if (t < 2 * NE) atomicAdd(&c1[d1[t - NE]], 1);
}

__global__ __launch_bounds__(1024) void k_scan1_2(const int* __restrict__ c0, const int* __restrict__ c1,
                                                  int* __restrict__ rp0, int* __restrict__ rp1,
                                                  int* __restrict__ b0, int* __restrict__ b1, int nscan) {
  __shared__ int tmp[1024];
  int rel = blockIdx.x >= nscan;
  int blk = rel ? blockIdx.x - nscan : blockIdx.x;
  const int* counts = rel ? c1 : c0;
  int* rp = rel ? rp1 : rp0;
  int* bsum = rel ? b1 : b0;
  int i = blk * 1024 + threadIdx.x;
  int v = (i < NN) ? counts[i] : 0;
  tmp[threadIdx.x] = v;
  __syncthreads();
  for (int off = 1; off < 1024; off <<= 1) {
    int t = (threadIdx.x >= off) ? tmp[threadIdx.x - off] : 0;
    __syncthreads();
    tmp[threadIdx.x] += t;
    __syncthreads();
  }
  if (i < NN) rp[i] = tmp[threadIdx.x] - v;  // block-local exclusive
  if (threadIdx.x == 1023) bsum[blk] = tmp[1023];
}

__global__ __launch_bounds__(128) void k_scan2_2(int* __restrict__ b0, int* __restrict__ b1, int nb) {
  int rel = threadIdx.x >> 6;
  int l = threadIdx.x & 63;
  int* bsum = rel ? b1 : b0;
  int orig = (l < nb) ? bsum[l] : 0;
  int v = orig;
#pragma unroll
  for (int off = 1; off < 64; off <<= 1) {
    int t = __shfl_up(v, off);
    if (l >= off) v += t;
  }
  if (l < nb) bsum[l] = v - orig;  // exclusive
}

__global__ __launch_bounds__(1024) void k_scan3_2(int* __restrict__ rp0, int* __restrict__ rp1,
                                                  const int* __restrict__ b0, const int* __restrict__ b1,
                                                  int nscan) {
  int rel = blockIdx.x >= nscan;
  int blk = rel ? blockIdx.x - nscan : blockIdx.x;
  int* rp = rel ? rp1 : rp0;
  const int* bsum = rel ? b1 : b0;
  int i = blk * 1024 + threadIdx.x;
  if (i < NN) rp[i] += bsum[blk];
  if (i == 0) rp[NN] = NE;
}

__global__ __launch_bounds__(256) void k_scatter2(
    const int* __restrict__ s0, const int* __restrict__ d0,
    const int* __restrict__ s1, const int* __restrict__ d1,
    const int* __restrict__ rp0, const int* __restrict__ rp1,
    int* __restrict__ f0, int* __restrict__ f1,
    int* __restrict__ cs0, int* __restrict__ cs1) {
  int t = blockIdx.x * 256 + threadIdx.x;
  if (t < NE) {
    int d = d0[t];
    int pos = rp0[d] + atomicAdd(&f0[d], 1);
    cs0[pos] = s0[t];
  } else if (t < 2 * NE) {
    int e = t - NE;
    int d = d1[e];
    int pos = rp1[d] + atomicAdd(&f1[d], 1);
    cs1[pos] = s1[e];
  }
}

__device__ __forceinline__ float pick_h(float4 v, int h) {
  float r = v.x;
  r = (h == 1) ? v.y : r;
  r = (h == 2) ? v.z : r;
  r = (h == 3) ? v.w : r;
  return r;
}

// ---------- fused GAT aggregation, both relations per dispatch ----------
template <typename OT>
__global__ __launch_bounds__(256) void k_agg2(
    const int* __restrict__ rpA, const int* __restrict__ csA,
    const float* __restrict__ elA, const float* __restrict__ erA,
    const _Float16* __restrict__ ZA, const float* __restrict__ bA, OT* __restrict__ oA,
    const int* __restrict__ rpB, const int* __restrict__ csB,
    const float* __restrict__ elB, const float* __restrict__ erB,
    const _Float16* __restrict__ ZB, const float* __restrict__ bB, OT* __restrict__ oB) {
  __shared__ float exs[4][256];
  __shared__ int ssrc[4][64];
  int nb = (NN + 3) / 4;
  int rel = blockIdx.x >= nb;
  int bid = rel ? blockIdx.x - nb : blockIdx.x;
  const int* rp = rel ? rpB : rpA;
  const int* csrc = rel ? csB : csA;
  const float* el = rel ? elB : elA;
  const float* er = rel ? erB : erA;
  const _Float16* Z = rel ? ZB : ZA;
  const float* bias = rel ? bB : bA;
  OT* out = rel ? oB : oA;

  int wv = threadIdx.x >> 6;
  int wid = bid * 4 + wv;
  if (wid >= NN) return;
  int lane = threadIdx.x & 63;
  int half = lane >> 5, l5 = lane & 31;
  int c0 = l5 * 8;      // 8 cols per lane (halves cover full row)
  int h = l5 >> 3;      // head for cols c0..c0+7
  int beg = rp[wid], end = rp[wid + 1];
  int deg = end - beg;

  if (deg == 0) {
    if (half == 0) {
      float4 b0 = *reinterpret_cast<const float4*>(bias + c0);
      float4 b1 = *reinterpret_cast<const float4*>(bias + c0 + 4);
      if constexpr (std::is_same<OT, float>::value) {
        float4* op = reinterpret_cast<float4*>(out + (size_t)wid * HF + c0);
        op[0] = b0; op[1] = b1;
      } else {
        f16x8 o = {(_Float16)b0.x, (_Float16)b0.y, (_Float16)b0.z, (_Float16)b0.w,
                   (_Float16)b1.x, (_Float16)b1.y, (_Float16)b1.z, (_Float16)b1.w};
        *reinterpret_cast<f16x8*>(out + (size_t)wid * HF + c0) = o;
      }
    }
    return;
  }

  if (deg <= 64) {
    // ---- pass A: lane i owns edge i ----
    int s = 0;
    float4 x = {-1e30f, -1e30f, -1e30f, -1e30f};
    float4 b = *reinterpret_cast<const float4*>(er + (size_t)wid * 4);
    if (lane < deg) {
      s = csrc[beg + lane];
      float4 a = reinterpret_cast<const float4*>(el)[s];
      x.x = a.x + b.x; x.x = x.x >= 0.f ? x.x : 0.2f * x.x;
      x.y = a.y + b.y; x.y = x.y >= 0.f ? x.y : 0.2f * x.y;
      x.z = a.z + b.z; x.z = x.z >= 0.f ? x.z : 0.2f * x.z;
      x.w = a.w + b.w; x.w = x.w >= 0.f ? x.w : 0.2f * x.w;
    }
    float4 m = x;
#pragma unroll
    for (int off = 32; off > 0; off >>= 1) {
      m.x = fmaxf(m.x, __shfl_xor(m.x, off));
      m.y = fmaxf(m.y, __shfl_xor(m.y, off));
      m.z = fmaxf(m.z, __shfl_xor(m.z, off));
      m.w = fmaxf(m.w, __shfl_xor(m.w, off));
    }
    float4 ex = {0.f, 0.f, 0.f, 0.f};
    if (lane < deg) {
      ex.x = __expf(x.x - m.x);
      ex.y = __expf(x.y - m.y);
      ex.z = __expf(x.z - m.z);
      ex.w = __expf(x.w - m.w);
    }
    float4 sm = ex;
#pragma unroll
    for (int off = 32; off > 0; off >>= 1) {
      sm.x += __shfl_xor(sm.x, off);
      sm.y += __shfl_xor(sm.y, off);
      sm.z += __shfl_xor(sm.z, off);
      sm.w += __shfl_xor(sm.w, off);
    }
    float inv = 1.0f / pick_h(sm, h);
    if (lane < deg) {
      *reinterpret_cast<float4*>(&exs[wv][lane * 4]) = ex;
      ssrc[wv][lane] = s;
    }
    // ---- pass B: halves own alternate edges, 4-group unroll -> 8 gathers in flight ----
    float a8[8] = {0.f, 0.f, 0.f, 0.f, 0.f, 0.f, 0.f, 0.f};
    int j = half;
#define AGG_STEP(J)                                                        \
    {                                                                      \
      int sj = ssrc[wv][(J)];                                              \
      float wj = exs[wv][(J) * 4 + h];                                     \
      f16x8 z = *reinterpret_cast<const f16x8*>(Z + (size_t)sj * HF + c0); \
      _Pragma("unroll")                                                    \
      for (int q = 0; q < 8; ++q) a8[q] += wj * (float)z[q];               \
    }
    for (; j + 6 < deg; j += 8) {
      AGG_STEP(j); AGG_STEP(j + 2); AGG_STEP(j + 4); AGG_STEP(j + 6);
    }
    for (; j < deg; j += 2) { AGG_STEP(j); }
#undef AGG_STEP
#pragma unroll
    for (int q = 0; q < 8; ++q) a8[q] += __shfl_xor(a8[q], 32);
    if (half == 0) {
      float4 b0 = *reinterpret_cast<const float4*>(bias + c0);
      float4 b1 = *reinterpret_cast<const float4*>(bias + c0 + 4);
      float r0 = a8[0] * inv + b0.x, r1 = a8[1] * inv + b0.y;
      float r2 = a8[2] * inv + b0.z, r3 = a8[3] * inv + b0.w;
      float r4 = a8[4] * inv + b1.x, r5 = a8[5] * inv + b1.y;
      float r6 = a8[6] * inv + b1.z, r7 = a8[7] * inv + b1.w;
      if constexpr (std::is_same<OT, float>::value) {
        float4* op = reinterpret_cast<float4*>(out + (size_t)wid * HF + c0);
        op[0] = (float4){r0, r1, r2, r3};
        op[1] = (float4){r4, r5, r6, r7};
      } else {
        f16x8 o = {(_Float16)r0, (_Float16)r1, (_Float16)r2, (_Float16)r3,
                   (_Float16)r4, (_Float16)r5, (_Float16)r6, (_Float16)r7};
        *reinterpret_cast<f16x8*>(out + (size_t)wid * HF + c0) = o;
      }
    }
    return;
  }

  // ---- rare fallback (deg > 64): uniform two-pass, full-wave f16x4 mapping ----
  {
    int c4 = lane * 4;
    int h4 = lane >> 4;
    float4 b = *reinterpret_cast<const float4*>(er + (size_t)wid * 4);
    float4 m = {-1e30f, -1e30f, -1e30f, -1e30f};
    for (int e = beg; e < end; ++e) {
      int s = csrc[e];
      float4 a = reinterpret_cast<const float4*>(el)[s];
      float4 x;
      x.x = a.x + b.x; x.x = x.x >= 0.f ? x.x : 0.2f * x.x;
      x.y = a.y + b.y; x.y = x.y >= 0.f ? x.y : 0.2f * x.y;
      x.z = a.z + b.z; x.z = x.z >= 0.f ? x.z : 0.2f * x.z;
      x.w = a.w + b.w; x.w = x.w >= 0.f ? x.w : 0.2f * x.w;
      m.x = fmaxf(m.x, x.x); m.y = fmaxf(m.y, x.y);
      m.z = fmaxf(m.z, x.z); m.w = fmaxf(m.w, x.w);
    }
    float4 sm = {0.f, 0.f, 0.f, 0.f};
    float4 acc = {0.f, 0.f, 0.f, 0.f};
    for (int e = beg; e < end; ++e) {
      int s = csrc[e];
      float4 a = reinterpret_cast<const float4*>(el)[s];
      float4 x;
      x.x = a.x + b.x; x.x = x.x >= 0.f ? x.x : 0.2f * x.x;
      x.y = a.y + b.y; x.y = x.y >= 0.f ? x.y : 0.2f * x.y;
      x.z = a.z + b.z; x.z = x.z >= 0.f ? x.z : 0.2f * x.z;
      x.w = a.w + b.w; x.w = x.w >= 0.f ? x.w : 0.2f * x.w;
      float4 exv;
      exv.x = __expf(x.x - m.x); exv.y = __expf(x.y - m.y);
      exv.z = __expf(x.z - m.z); exv.w = __expf(x.w - m.w);
      sm.x += exv.x; sm.y += exv.y; sm.z += exv.z; sm.w += exv.w;
      float w0 = pick_h(exv, h4);
      f16x4 z0 = *reinterpret_cast<const f16x4*>(Z + (size_t)s * HF + c4);
      acc.x += w0 * (float)z0.x;
      acc.y += w0 * (float)z0.y;
      acc.z += w0 * (float)z0.z;
      acc.w += w0 * (float)z0.w;
    }
    float inv = 1.0f / pick_h(sm, h4);
    float4 bv = *reinterpret_cast<const float4*>(bias + c4);
    float r0 = acc.x * inv + bv.x, r1 = acc.y * inv + bv.y;
    float r2 = acc.z * inv + bv.z, r3 = acc.w * inv + bv.w;
    if constexpr (std::is_same<OT, float>::value) {
      *reinterpret_cast<float4*>(out + (size_t)wid * HF + c4) = (float4){r0, r1, r2, r3};
    } else {
      f16x4 o = {(_Float16)r0, (_Float16)r1, (_Float16)r2, (_Float16)r3};
      *reinterpret_cast<f16x4*>(out + (size_t)wid * HF + c4) = o;
    }
  }
}

// ---------- batchnorm stats, both sides per dispatch ----------
__global__ __launch_bounds__(256) void k_bn_stats2(const _Float16* __restrict__ XU,
                                                   const _Float16* __restrict__ XI,
                                                   float* __restrict__ su, float* __restrict__ qu,
                                                   float* __restrict__ si, float* __restrict__ qi) {
  int rel = blockIdx.x >> 9;  // grid = 1024
  int blk = blockIdx.x & 511;
  const _Float16* X = rel ? XI : XU;
  float* sums = rel ? si : su;
  float* sqs = rel ? qi : qu;
  int c = threadIdx.x;
  float s = 0.f, q = 0.f;
  for (int r = blk; r < NN; r += 512) {
    float v = (float)X[(size_t)r * HF + c];
    s += v;
    q += v * v;
  }
  atomicAdd(&sums[c], s);
  atomicAdd(&sqs[c], q);
}

extern "C" void kernel_launch(void* const* d_in, const int* in_sizes, int n_in,
                              void* d_out, int out_size, void* d_ws, size_t ws_size,
                              hipStream_t stream) {
  (void)in_sizes; (void)n_in; (void)out_size; (void)ws_size;
  const float* x_user = (const float*)d_in[0];
  const float* x_item = (const float*)d_in[1];
  const int* ui_src = (const int*)d_in[2];
  const int* ui_dst = (const int*)d_in[3];
  const int* iu_src = (const int*)d_in[4];
  const int* iu_dst = (const int*)d_in[5];
  const float *Wp[4], *alp[4], *arp[4], *bp[4];
  for (int l = 0; l < 4; ++l) {
    Wp[l]  = (const float*)d_in[6 + 4 * l];
    alp[l] = (const float*)d_in[7 + 4 * l];
    arp[l] = (const float*)d_in[8 + 4 * l];
    bp[l]  = (const float*)d_in[9 + 4 * l];
  }
  const float* bng = (const float*)d_in[22];
  const float* bnb = (const float*)d_in[23];

  char* w = (char*)d_ws;
  auto alloc = [&](size_t bytes) -> void* {
    void* p = (void*)w;
    w += (bytes + 255) & ~(size_t)255;
    return p;
  };
  _Float16* XU16 = (_Float16*)alloc((size_t)NN * 128 * 2);
  _Float16* XI16 = (_Float16*)alloc((size_t)NN * 128 * 2);
  _Float16* Z0 = (_Float16*)alloc((size_t)NN * HF * 2);
  _Float16* Z1 = (_Float16*)alloc((size_t)NN * HF * 2);
  _Float16* RAW16U = (_Float16*)alloc((size_t)NN * HF * 2);
  _Float16* RAW16I = (_Float16*)alloc((size_t)NN * HF * 2);
  float* EL0 = (float*)alloc((size_t)NN * 4 * 4);
  float* ER0 = (float*)alloc((size_t)NN * 4 * 4);
  float* EL1 = (float*)alloc((size_t)NN * 4 * 4);
  float* ER1 = (float*)alloc((size_t)NN * 4 * 4);
  _Float16* WT = (_Float16*)alloc((size_t)8 * 65536 * 2);
  float* ATTN = (float*)alloc((size_t)8 * 1024 * 4);   // [l*2+r][256][4]
  int* rp_ui = (int*)alloc((size_t)(NN + 1) * 4);
  int* rp_iu = (int*)alloc((size_t)(NN + 1) * 4);
  int* csrc_ui = (int*)alloc((size_t)NE * 4);
  int* csrc_iu = (int*)alloc((size_t)NE * 4);
  int* counts = (int*)alloc((size_t)4 * NN * 4);  // counts_ui | counts_iu | fill_ui | fill_iu
  int* bsum_ui = (int*)alloc((size_t)64 * 4);
  int* bsum_iu = (int*)alloc((size_t)64 * 4);
  float* stats = (float*)alloc((size_t)6 * 512 * 4);

  int* counts_ui = counts;
  int* counts_iu = counts + NN;
  int* fill_ui = counts + 2 * NN;
  int* fill_iu = counts + 3 * NN;

  hipMemsetAsync(counts, 0, (size_t)4 * NN * 4, stream);
  hipMemsetAsync(stats, 0, (size_t)6 * 512 * 4, stream);

  // input conversion (one dispatch)
  int n4 = NN * 128 / 4;
  k_tofp16_2<<<(2 * n4 + 255) / 256, 256, 0, stream>>>(x_user, x_item, XU16, XI16, n4);

  // all weight transposes (one dispatch)
  TArgs ta;
  int cum = 0;
  for (int l = 0; l < 4; ++l) {
    int K = (l == 0) ? 128 : 256;
    for (int r = 0; r < 2; ++r) {
      int s = l * 2 + r;
      ta.W[s] = Wp[l] + (size_t)r * K * HF;
      ta.dst[s] = WT + (size_t)s * 65536;
      ta.K[s] = K;
      ta.cum[s] = cum;
      cum += K * 256;
    }
  }
  ta.cum[8] = cum;
  k_transpose_all<<<(cum + 255) / 256, 256, 0, stream>>>(ta);

  // all W.ar attn tables (one dispatch)
  k_makeattn_all<<<(8 * 256 * 4 + 255) / 256, 256, 0, stream>>>(
      Wp[0], Wp[1], Wp[2], Wp[3], arp[0], arp[1], arp[2], arp[3], ATTN);

  // CSR build (both relations per dispatch)
  int egrid2 = (2 * NE + 255) / 256;
  int nscan = (NN + 1023) / 1024;
  k_hist2<<<egrid2, 256, 0, stream>>>(ui_dst, iu_dst, counts_ui, counts_iu);
  k_scan1_2<<<2 * nscan, 1024, 0, stream>>>(counts_ui, counts_iu, rp_ui, rp_iu, bsum_ui, bsum_iu, nscan);
  k_scan2_2<<<1, 128, 0, stream>>>(bsum_ui, bsum_iu, nscan);
  k_scan3_2<<<2 * nscan, 1024, 0, stream>>>(rp_ui, rp_iu, bsum_ui, bsum_iu, nscan);
  k_scatter2<<<egrid2, 256, 0, stream>>>(ui_src, ui_dst, iu_src, iu_dst, rp_ui, rp_iu,
                                         fill_ui, fill_iu, csrc_ui, csrc_iu);

  int agrid = (NN + 3) / 4;
  float* out_user = (float*)d_out;
  float* out_item = (float*)d_out + (size_t)NN * HF;

  for (int l = 0; l < 4; ++l) {
    int K = (l == 0) ? 128 : 256;
    int mgrid = (NN + 63) / 64;

    GArgs ga;
    ga.A0 = (l == 0) ? XU16 : RAW16U;
    ga.A1 = (l == 0) ? XI16 : RAW16I;
    ga.Wt0 = WT + (size_t)(l * 2 + 0) * 65536;
    ga.Wt1 = WT + (size_t)(l * 2 + 1) * 65536;
    ga.Z0 = Z0; ga.Z1 = Z1;
    ga.al0 = alp[l] + 0; ga.al1 = alp[l] + 256;
    ga.EL0 = EL0; ga.EL1 = EL1;
    ga.war_s0 = ATTN + (size_t)(l * 2 + 1) * 1024;  // side0 (A=hu) -> er1 = hu . (W1.ar1)
    ga.war_s1 = ATTN + (size_t)(l * 2 + 0) * 1024;  // side1 (A=hi) -> er0 = hi . (W0.ar0)
    ga.ER_s0 = ER1; ga.ER_s1 = ER0;
    if (l > 0) {
      const float* su = stats + (size_t)((l - 1) * 2 + 0) * 512;
      const float* si = stats + (size_t)((l - 1) * 2 + 1) * 512;
      ga.su = su; ga.qu = su + 256;
      ga.si = si; ga.qi = si + 256;
      ga.gu = bng + (size_t)((l - 1) * 2 + 0) * 256;
      ga.bu = bnb + (size_t)((l - 1) * 2 + 0) * 256;
      ga.gi = bng + (size_t)((l - 1) * 2 + 1) * 256;
      ga.bi = bnb + (size_t)((l - 1) * 2 + 1) * 256;
      ga.mode = (l == 3) ? 2 : 1;
    } else {
      ga.su = ga.qu = ga.si = ga.qi = ga.gu = ga.bu = ga.gi = ga.bi = nullptr;
      ga.mode = 0;
    }
    ga.M = NN; ga.K = K;
    k_gemm3<<<2 * mgrid, 256, 0, stream>>>(ga);

    // aggregation pair: u->i (dst items, Z0) and i->u (dst users, Z1)
    if (l < 3)
      k_agg2<_Float16><<<2 * agrid, 256, 0, stream>>>(
          rp_ui, csrc_ui, EL0, ER0, Z0, bp[l] + 0, RAW16I,
          rp_iu, csrc_iu, EL1, ER1, Z1, bp[l] + 256, RAW16U);
    else
      k_agg2<float><<<2 * agrid, 256, 0, stream>>>(
          rp_ui, csrc_ui, EL0, ER0, Z0, bp[l] + 0, out_item,
          rp_iu, csrc_iu, EL1, ER1, Z1, bp[l] + 256, out_user);

    if (l < 3) {
      float* su = stats + (size_t)(l * 2 + 0) * 512;
      float* qu = su + 256;
      float* si = stats + (size_t)(l * 2 + 1) * 512;
      float* qi = si + 256;
      k_bn_stats2<<<1024, 256, 0, stream>>>(RAW16U, RAW16I, su, qu, si, qi);
    }
  }
}

// Round 9
// 1244.389 us; speedup vs baseline: 1.1641x; 1.1641x over previous
//
#include <hip/hip_runtime.h>
#include <hip/hip_bf16.h>
#include <type_traits>

#define NN 50000     // nodes per side (users == items == 50000)
#define NE 600000    // edges per relation
#define HF 256       // hidden features

typedef float f32x4 __attribute__((ext_vector_type(4)));
typedef _Float16 f16x8 __attribute__((ext_vector_type(8)));
typedef _Float16 f16x4 __attribute__((ext_vector_type(4)));

__device__ __forceinline__ float actf(float v, int mode) {
  if (mode == 1) return v >= 0.f ? v : 0.01f * v;
  if (mode == 2) return tanhf(v);
  return v;
}

// ---------- fp32 -> fp16 convert, both inputs in one dispatch ----------
__global__ __launch_bounds__(256) void k_tofp16_2(const float* __restrict__ A,
                                                  const float* __restrict__ B,
                                                  _Float16* __restrict__ OA,
                                                  _Float16* __restrict__ OB, int n4) {
  int i = blockIdx.x * 256 + threadIdx.x;
  const float* X = (i < n4) ? A : B;
  _Float16* Y = (i < n4) ? OA : OB;
  int j = (i < n4) ? i : i - n4;
  if (j < n4) {
    float4 v = reinterpret_cast<const float4*>(X)[j];
    f16x4 o = {(_Float16)v.x, (_Float16)v.y, (_Float16)v.z, (_Float16)v.w};
    reinterpret_cast<f16x4*>(Y)[j] = o;
  }
}

// ---------- all 8 W[K][256] -> Wt[256][K] transposes in one dispatch ----------
struct TArgs {
  const float* W[8];
  _Float16* dst[8];
  int K[8];
  int cum[9];
};
__global__ __launch_bounds__(256) void k_transpose_all(TArgs t) {
  int idx = blockIdx.x * 256 + threadIdx.x;
#pragma unroll
  for (int s = 0; s < 8; ++s) {
    if (idx >= t.cum[s] && idx < t.cum[s + 1]) {
      int local = idx - t.cum[s];
      int K = t.K[s];
      int k = local >> 8;
      int n = local & 255;
      t.dst[s][(size_t)n * K + k] = (_Float16)t.W[s][local];
    }
  }
}

// ---------- all W.ar attn tables in one dispatch: out[(l*2+r)*1024 + k*4 + h] ----------
__global__ __launch_bounds__(256) void k_makeattn_all(
    const float* __restrict__ W1, const float* __restrict__ W2,
    const float* __restrict__ W3, const float* __restrict__ W4,
    const float* __restrict__ ar1, const float* __restrict__ ar2,
    const float* __restrict__ ar3, const float* __restrict__ ar4,
    float* __restrict__ out) {
  int idx = blockIdx.x * 256 + threadIdx.x;
  if (idx >= 8 * 256 * 4) return;
  int h = idx & 3;
  int k = (idx >> 2) & 255;
  int s = idx >> 10;  // l*2+r
  int l = s >> 1, r = s & 1;
  int K = (l == 0) ? 128 : 256;
  if (k >= K) return;
  const float* W = (l == 0 ? W1 : l == 1 ? W2 : l == 2 ? W3 : W4) + (size_t)r * K * 256;
  const float* a = (l == 0 ? ar1 : l == 1 ? ar2 : l == 2 ? ar3 : ar4) + r * 256 + h * 64;
  const float* wrow = W + (size_t)k * 256 + h * 64;
  float sum = 0.f;
#pragma unroll 8
  for (int d = 0; d < 64; ++d) sum += wrow[d] * a[d];
  out[s * 1024 + k * 4 + h] = sum;
}

// ---------- BN finalize: scale/shift per column, both sides (grid = 2 blocks) ----------
__global__ __launch_bounds__(256) void k_bnfinal(
    const float* __restrict__ su, const float* __restrict__ qu,
    const float* __restrict__ si, const float* __restrict__ qi,
    const float* __restrict__ gu, const float* __restrict__ bu,
    const float* __restrict__ gi, const float* __restrict__ bi,
    float* __restrict__ ssu, float* __restrict__ ssi) {
  int side = blockIdx.x;
  const float* sums = side ? si : su;
  const float* sqs = side ? qi : qu;
  const float* g = side ? gi : gu;
  const float* bt = side ? bi : bu;
  float* ss = side ? ssi : ssu;
  int c = threadIdx.x;
  const float invN = 1.0f / NN;
  float mu = sums[c] * invN;
  float var = sqs[c] * invN - mu * mu;
  float sc = rsqrtf(var + 1e-5f) * g[c];
  ss[c] = sc;
  ss[256 + c] = bt[c] - mu * sc;
}

// ---------- er GEMV, both relations in one dispatch; inline BN+act ----------
__global__ __launch_bounds__(256) void k_gemv_er2(const _Float16* __restrict__ Xi,
                                                  const _Float16* __restrict__ Xu,
                                                  const float* __restrict__ war0,
                                                  const float* __restrict__ war1,
                                                  float* __restrict__ ER0, float* __restrict__ ER1,
                                                  const float* __restrict__ ssi,
                                                  const float* __restrict__ ssu,
                                                  int K, int mode) {
  int nb = (NN + 3) / 4;
  int rel = blockIdx.x >= nb;
  int bid = rel ? blockIdx.x - nb : blockIdx.x;
  const _Float16* X = rel ? Xu : Xi;
  const float* wa = rel ? war1 : war0;
  const float* ss = rel ? ssu : ssi;
  float* out = rel ? ER1 : ER0;
  int wid = bid * 4 + (threadIdx.x >> 6);
  if (wid >= NN) return;
  int lane = threadIdx.x & 63;
  float p0 = 0.f, p1 = 0.f, p2 = 0.f, p3 = 0.f;
  int k0 = lane * 4;
  if (k0 < K) {
    f16x4 x = *reinterpret_cast<const f16x4*>(X + (size_t)wid * K + k0);
    float xv[4] = {(float)x.x, (float)x.y, (float)x.z, (float)x.w};
    if (mode) {
      float4 sc = *reinterpret_cast<const float4*>(ss + k0);
      float4 sh = *reinterpret_cast<const float4*>(ss + 256 + k0);
      xv[0] = actf(xv[0] * sc.x + sh.x, mode);
      xv[1] = actf(xv[1] * sc.y + sh.y, mode);
      xv[2] = actf(xv[2] * sc.z + sh.z, mode);
      xv[3] = actf(xv[3] * sc.w + sh.w, mode);
    }
#pragma unroll
    for (int j = 0; j < 4; ++j) {
      float4 wv = *reinterpret_cast<const float4*>(wa + (k0 + j) * 4);
      p0 += xv[j] * wv.x; p1 += xv[j] * wv.y; p2 += xv[j] * wv.z; p3 += xv[j] * wv.w;
    }
  }
#pragma unroll
  for (int off = 32; off > 0; off >>= 1) {
    p0 += __shfl_down(p0, off); p1 += __shfl_down(p1, off);
    p2 += __shfl_down(p2, off); p3 += __shfl_down(p3, off);
  }
  if (lane == 0)
    *reinterpret_cast<float4*>(out + (size_t)wid * 4) = (float4){p0, p1, p2, p3};
}

// ---------- GEMM pair with BN(+act) applied on A-load (precomputed scale/shift); el epilogue ----------
struct GArgs {
  const _Float16* A0; const _Float16* A1;     // raw inputs (pre-BN for mode>0)
  const _Float16* Wt0; const _Float16* Wt1;
  _Float16* Z0; _Float16* Z1;
  const float* al0; const float* al1;
  float* EL0; float* EL1;
  const float* ssu; const float* ssi;         // [scale 256 | shift 256] per side
  int M, K, mode;                             // mode: 0 none, 1 leaky0.01, 2 tanh
};

__global__ __launch_bounds__(256) void k_gemm3(GArgs ga) {
  int mgrid = (ga.M + 63) / 64;
  int side = blockIdx.x >= mgrid;
  int bid = side ? blockIdx.x - mgrid : blockIdx.x;
  const _Float16* A = side ? ga.A1 : ga.A0;
  const _Float16* Wt = side ? ga.Wt1 : ga.Wt0;
  _Float16* Z = side ? ga.Z1 : ga.Z0;
  const float* al = side ? ga.al1 : ga.al0;
  float* EL = side ? ga.EL1 : ga.EL0;
  const float* ss = side ? ga.ssi : ga.ssu;
  const int K = ga.K, M = ga.M, mode = ga.mode;

  int wave = threadIdx.x >> 6;
  int lane = threadIdx.x & 63;
  int lr = lane & 15;   // fragment row (A) / col (B)
  int kg = lane >> 4;   // k-group: k = kg*8 + j
  int row0 = bid * 64;
  int col0 = wave * 64;
  f32x4 acc[4][4];
#pragma unroll
  for (int i = 0; i < 4; ++i)
#pragma unroll
    for (int j = 0; j < 4; ++j) acc[i][j] = (f32x4){0.f, 0.f, 0.f, 0.f};

  for (int k0 = 0; k0 < K; k0 += 32) {
    float sc[8], sh[8];
    if (mode) {
      int kk = k0 + kg * 8;
      float4 a0 = *reinterpret_cast<const float4*>(ss + kk);
      float4 a1 = *reinterpret_cast<const float4*>(ss + kk + 4);
      float4 b0 = *reinterpret_cast<const float4*>(ss + 256 + kk);
      float4 b1 = *reinterpret_cast<const float4*>(ss + 256 + kk + 4);
      sc[0] = a0.x; sc[1] = a0.y; sc[2] = a0.z; sc[3] = a0.w;
      sc[4] = a1.x; sc[5] = a1.y; sc[6] = a1.z; sc[7] = a1.w;
      sh[0] = b0.x; sh[1] = b0.y; sh[2] = b0.z; sh[3] = b0.w;
      sh[4] = b1.x; sh[5] = b1.y; sh[6] = b1.z; sh[7] = b1.w;
    }
    f16x8 af[4], bfr[4];
#pragma unroll
    for (int mt = 0; mt < 4; ++mt) {
      int r = row0 + mt * 16 + lr;
      if (r >= M) r = M - 1;  // clamp loads; stores are guarded
      f16x8 raw = *reinterpret_cast<const f16x8*>(A + (size_t)r * K + k0 + kg * 8);
      if (mode) {
        f16x8 o;
#pragma unroll
        for (int j = 0; j < 8; ++j)
          o[j] = (_Float16)actf((float)raw[j] * sc[j] + sh[j], mode);
        af[mt] = o;
      } else {
        af[mt] = raw;
      }
    }
#pragma unroll
    for (int ct = 0; ct < 4; ++ct) {
      int c = col0 + ct * 16 + lr;
      bfr[ct] = *reinterpret_cast<const f16x8*>(Wt + (size_t)c * K + k0 + kg * 8);
    }
#pragma unroll
    for (int mt = 0; mt < 4; ++mt)
#pragma unroll
      for (int ct = 0; ct < 4; ++ct)
        acc[mt][ct] = __builtin_amdgcn_mfma_f32_16x16x32_f16(af[mt], bfr[ct], acc[mt][ct], 0, 0, 0);
  }
  // C/D layout: col = lane&15, row = (lane>>4)*4 + reg
#pragma unroll
  for (int mt = 0; mt < 4; ++mt) {
#pragma unroll
    for (int r = 0; r < 4; ++r) {
      int row = row0 + mt * 16 + kg * 4 + r;
      if (row < M) {
#pragma unroll
        for (int ct = 0; ct < 4; ++ct) {
          int col = col0 + ct * 16 + lr;
          Z[(size_t)row * HF + col] = (_Float16)acc[mt][ct][r];
        }
      }
    }
  }
  // fused el epilogue: el[row][h=wave] = sum_col z[row][col] * al[col]
  float al4[4];
#pragma unroll
  for (int ct = 0; ct < 4; ++ct) al4[ct] = al[wave * 64 + ct * 16 + lr];
#pragma unroll
  for (int mt = 0; mt < 4; ++mt) {
#pragma unroll
    for (int r = 0; r < 4; ++r) {
      float p = acc[mt][0][r] * al4[0] + acc[mt][1][r] * al4[1] +
                acc[mt][2][r] * al4[2] + acc[mt][3][r] * al4[3];
#pragma unroll
      for (int off = 1; off < 16; off <<= 1) p += __shfl_xor(p, off);
      int row = row0 + mt * 16 + kg * 4 + r;
      if (lr == 0 && row < M) EL[(size_t)row * 4 + wave] = p;
    }
  }
}

// ---------- CSR build (both relations per dispatch) ----------
__global__ __launch_bounds__(256) void k_hist2(const int* __restrict__ d0, const int* __restrict__ d1,
                                               int* __restrict__ c0, int* __restrict__ c1) {
  int t = blockIdx.x * 256 + threadIdx.x;
  if (t < NE) atomicAdd(&c0[d0[t]], 1);
  else if (t < 2 * NE) atomicAdd(&c1[d1[t - NE]], 1);
}

__global__ __launch_bounds__(1024) void k_scan1_2(const int* __restrict__ c0, const int* __restrict__ c1,
                                                  int* __restrict__ rp0, int* __restrict__ rp1,
                                                  int* __restrict__ b0, int* __restrict__ b1, int nscan) {
  __shared__ int tmp[1024];
  int rel = blockIdx.x >= nscan;
  int blk = rel ? blockIdx.x - nscan : blockIdx.x;
  const int* counts = rel ? c1 : c0;
  int* rp = rel ? rp1 : rp0;
  int* bsum = rel ? b1 : b0;
  int i = blk * 1024 + threadIdx.x;
  int v = (i < NN) ? counts[i] : 0;
  tmp[threadIdx.x] = v;
  __syncthreads();
  for (int off = 1; off < 1024; off <<= 1) {
    int t = (threadIdx.x >= off) ? tmp[threadIdx.x - off] : 0;
    __syncthreads();
    tmp[threadIdx.x] += t;
    __syncthreads();
  }
  if (i < NN) rp[i] = tmp[threadIdx.x] - v;  // block-local exclusive
  if (threadIdx.x == 1023) bsum[blk] = tmp[1023];
}

__global__ __launch_bounds__(128) void k_scan2_2(int* __restrict__ b0, int* __restrict__ b1, int nb) {
  int rel = threadIdx.x >> 6;
  int l = threadIdx.x & 63;
  int* bsum = rel ? b1 : b0;
  int orig = (l < nb) ? bsum[l] : 0;
  int v = orig;
#pragma unroll
  for (int off = 1; off < 64; off <<= 1) {
    int t = __shfl_up(v, off);
    if (l >= off) v += t;
  }
  if (l < nb) bsum[l] = v - orig;  // exclusive
}

__global__ __launch_bounds__(1024) void k_scan3_2(int* __restrict__ rp0, int* __restrict__ rp1,
                                                  const int* __restrict__ b0, const int* __restrict__ b1,
                                                  int nscan) {
  int rel = blockIdx.x >= nscan;
  int blk = rel ? blockIdx.x - nscan : blockIdx.x;
  int* rp = rel ? rp1 : rp0;
  const int* bsum = rel ? b1 : b0;
  int i = blk * 1024 + threadIdx.x;
  if (i < NN) rp[i] += bsum[blk];
  if (i == 0) rp[NN] = NE;
}

__global__ __launch_bounds__(256) void k_scatter2(
    const int* __restrict__ s0, const int* __restrict__ d0,
    const int* __restrict__ s1, const int* __restrict__ d1,
    const int* __restrict__ rp0, const int* __restrict__ rp1,
    int* __restrict__ f0, int* __restrict__ f1,
    int* __restrict__ cs0, int* __restrict__ cs1) {
  int t = blockIdx.x * 256 + threadIdx.x;
  if (t < NE) {
    int d = d0[t];
    int pos = rp0[d] + atomicAdd(&f0[d], 1);
    cs0[pos] = s0[t];
  } else if (t < 2 * NE) {
    int e = t - NE;
    int d = d1[e];
    int pos = rp1[d] + atomicAdd(&f1[d], 1);
    cs1[pos] = s1[e];
  }
}

__device__ __forceinline__ float pick_h(float4 v, int h) {
  float r = v.x;
  r = (h == 1) ? v.y : r;
  r = (h == 2) ? v.z : r;
  r = (h == 3) ? v.w : r;
  return r;
}

// ---------- fused GAT aggregation, both relations per dispatch ----------
template <typename OT>
__global__ __launch_bounds__(256) void k_agg2(
    const int* __restrict__ rpA, const int* __restrict__ csA,
    const float* __restrict__ elA, const float* __restrict__ erA,
    const _Float16* __restrict__ ZA, const float* __restrict__ bA, OT* __restrict__ oA,
    const int* __restrict__ rpB, const int* __restrict__ csB,
    const float* __restrict__ elB, const float* __restrict__ erB,
    const _Float16* __restrict__ ZB, const float* __restrict__ bB, OT* __restrict__ oB) {
  __shared__ float exs[4][256];
  __shared__ int ssrc[4][64];
  int nb = (NN + 3) / 4;
  int rel = blockIdx.x >= nb;
  int bid = rel ? blockIdx.x - nb : blockIdx.x;
  const int* rp = rel ? rpB : rpA;
  const int* csrc = rel ? csB : csA;
  const float* el = rel ? elB : elA;
  const float* er = rel ? erB : erA;
  const _Float16* Z = rel ? ZB : ZA;
  const float* bias = rel ? bB : bA;
  OT* out = rel ? oB : oA;

  int wv = threadIdx.x >> 6;
  int wid = bid * 4 + wv;
  if (wid >= NN) return;
  int lane = threadIdx.x & 63;
  int half = lane >> 5, l5 = lane & 31;
  int c0 = l5 * 8;      // 8 cols per lane (halves cover full row)
  int h = l5 >> 3;      // head for cols c0..c0+7
  int beg = rp[wid], end = rp[wid + 1];
  int deg = end - beg;

  if (deg == 0) {
    if (half == 0) {
      float4 b0 = *reinterpret_cast<const float4*>(bias + c0);
      float4 b1 = *reinterpret_cast<const float4*>(bias + c0 + 4);
      if constexpr (std::is_same<OT, float>::value) {
        float4* op = reinterpret_cast<float4*>(out + (size_t)wid * HF + c0);
        op[0] = b0; op[1] = b1;
      } else {
        f16x8 o = {(_Float16)b0.x, (_Float16)b0.y, (_Float16)b0.z, (_Float16)b0.w,
                   (_Float16)b1.x, (_Float16)b1.y, (_Float16)b1.z, (_Float16)b1.w};
        *reinterpret_cast<f16x8*>(out + (size_t)wid * HF + c0) = o;
      }
    }
    return;
  }

  if (deg <= 64) {
    // ---- pass A: lane i owns edge i ----
    int s = 0;
    float4 x = {-1e30f, -1e30f, -1e30f, -1e30f};
    float4 b = *reinterpret_cast<const float4*>(er + (size_t)wid * 4);
    if (lane < deg) {
      s = csrc[beg + lane];
      float4 a = reinterpret_cast<const float4*>(el)[s];
      x.x = a.x + b.x; x.x = x.x >= 0.f ? x.x : 0.2f * x.x;
      x.y = a.y + b.y; x.y = x.y >= 0.f ? x.y : 0.2f * x.y;
      x.z = a.z + b.z; x.z = x.z >= 0.f ? x.z : 0.2f * x.z;
      x.w = a.w + b.w; x.w = x.w >= 0.f ? x.w : 0.2f * x.w;
    }
    float4 m = x;
#pragma unroll
    for (int off = 32; off > 0; off >>= 1) {
      m.x = fmaxf(m.x, __shfl_xor(m.x, off));
      m.y = fmaxf(m.y, __shfl_xor(m.y, off));
      m.z = fmaxf(m.z, __shfl_xor(m.z, off));
      m.w = fmaxf(m.w, __shfl_xor(m.w, off));
    }
    float4 ex = {0.f, 0.f, 0.f, 0.f};
    if (lane < deg) {
      ex.x = __expf(x.x - m.x);
      ex.y = __expf(x.y - m.y);
      ex.z = __expf(x.z - m.z);
      ex.w = __expf(x.w - m.w);
    }
    float4 sm = ex;
#pragma unroll
    for (int off = 32; off > 0; off >>= 1) {
      sm.x += __shfl_xor(sm.x, off);
      sm.y += __shfl_xor(sm.y, off);
      sm.z += __shfl_xor(sm.z, off);
      sm.w += __shfl_xor(sm.w, off);
    }
    float inv = 1.0f / pick_h(sm, h);
    if (lane < deg) {
      *reinterpret_cast<float4*>(&exs[wv][lane * 4]) = ex;
      ssrc[wv][lane] = s;
    }
    // ---- pass B: halves own alternate edges, 4-group unroll -> 8 gathers in flight ----
    float a8[8] = {0.f, 0.f, 0.f, 0.f, 0.f, 0.f, 0.f, 0.f};
    int j = half;
#define AGG_STEP(J)                                                        \
    {                                                                      \
      int sj = ssrc[wv][(J)];                                              \
      float wj = exs[wv][(J) * 4 + h];                                     \
      f16x8 z = *reinterpret_cast<const f16x8*>(Z + (size_t)sj * HF + c0); \
      _Pragma("unroll")                                                    \
      for (int q = 0; q < 8; ++q) a8[q] += wj * (float)z[q];               \
    }
    for (; j + 6 < deg; j += 8) {
      AGG_STEP(j); AGG_STEP(j + 2); AGG_STEP(j + 4); AGG_STEP(j + 6);
    }
    for (; j < deg; j += 2) { AGG_STEP(j); }
#undef AGG_STEP
#pragma unroll
    for (int q = 0; q < 8; ++q) a8[q] += __shfl_xor(a8[q], 32);
    if (half == 0) {
      float4 b0 = *reinterpret_cast<const float4*>(bias + c0);
      float4 b1 = *reinterpret_cast<const float4*>(bias + c0 + 4);
      float r0 = a8[0] * inv + b0.x, r1 = a8[1] * inv + b0.y;
      float r2 = a8[2] * inv + b0.z, r3 = a8[3] * inv + b0.w;
      float r4 = a8[4] * inv + b1.x, r5 = a8[5] * inv + b1.y;
      float r6 = a8[6] * inv + b1.z, r7 = a8[7] * inv + b1.w;
      if constexpr (std::is_same<OT, float>::value) {
        float4* op = reinterpret_cast<float4*>(out + (size_t)wid * HF + c0);
        op[0] = (float4){r0, r1, r2, r3};
        op[1] = (float4){r4, r5, r6, r7};
      } else {
        f16x8 o = {(_Float16)r0, (_Float16)r1, (_Float16)r2, (_Float16)r3,
                   (_Float16)r4, (_Float16)r5, (_Float16)r6, (_Float16)r7};
        *reinterpret_cast<f16x8*>(out + (size_t)wid * HF + c0) = o;
      }
    }
    return;
  }

  // ---- rare fallback (deg > 64): uniform two-pass, full-wave f16x4 mapping ----
  {
    int c4 = lane * 4;
    int h4 = lane >> 4;
    float4 b = *reinterpret_cast<const float4*>(er + (size_t)wid * 4);
    float4 m = {-1e30f, -1e30f, -1e30f, -1e30f};
    for (int e = beg; e < end; ++e) {
      int s = csrc[e];
      float4 a = reinterpret_cast<const float4*>(el)[s];
      float4 x;
      x.x = a.x + b.x; x.x = x.x >= 0.f ? x.x : 0.2f * x.x;
      x.y = a.y + b.y; x.y = x.y >= 0.f ? x.y : 0.2f * x.y;
      x.z = a.z + b.z; x.z = x.z >= 0.f ? x.z : 0.2f * x.z;
      x.w = a.w + b.w; x.w = x.w >= 0.f ? x.w : 0.2f * x.w;
      m.x = fmaxf(m.x, x.x); m.y = fmaxf(m.y, x.y);
      m.z = fmaxf(m.z, x.z); m.w = fmaxf(m.w, x.w);
    }
    float4 sm = {0.f, 0.f, 0.f, 0.f};
    float4 acc = {0.f, 0.f, 0.f, 0.f};
    for (int e = beg; e < end; ++e) {
      int s = csrc[e];
      float4 a = reinterpret_cast<const float4*>(el)[s];
      float4 x;
      x.x = a.x + b.x; x.x = x.x >= 0.f ? x.x : 0.2f * x.x;
      x.y = a.y + b.y; x.y = x.y >= 0.f ? x.y : 0.2f * x.y;
      x.z = a.z + b.z; x.z = x.z >= 0.f ? x.z : 0.2f * x.z;
      x.w = a.w + b.w; x.w = x.w >= 0.f ? x.w : 0.2f * x.w;
      float4 exv;
      exv.x = __expf(x.x - m.x); exv.y = __expf(x.y - m.y);
      exv.z = __expf(x.z - m.z); exv.w = __expf(x.w - m.w);
      sm.x += exv.x; sm.y += exv.y; sm.z += exv.z; sm.w += exv.w;
      float w0 = pick_h(exv, h4);
      f16x4 z0 = *reinterpret_cast<const f16x4*>(Z + (size_t)s * HF + c4);
      acc.x += w0 * (float)z0.x;
      acc.y += w0 * (float)z0.y;
      acc.z += w0 * (float)z0.z;
      acc.w += w0 * (float)z0.w;
    }
    float inv = 1.0f / pick_h(sm, h4);
    float4 bv = *reinterpret_cast<const float4*>(bias + c4);
    float r0 = acc.x * inv + bv.x, r1 = acc.y * inv + bv.y;
    float r2 = acc.z * inv + bv.z, r3 = acc.w * inv + bv.w;
    if constexpr (std::is_same<OT, float>::value) {
      *reinterpret_cast<float4*>(out + (size_t)wid * HF + c4) = (float4){r0, r1, r2, r3};
    } else {
      f16x4 o = {(_Float16)r0, (_Float16)r1, (_Float16)r2, (_Float16)r3};
      *reinterpret_cast<f16x4*>(out + (size_t)wid * HF + c4) = o;
    }
  }
}

// ---------- batchnorm stats, both sides per dispatch ----------
__global__ __launch_bounds__(256) void k_bn_stats2(const _Float16* __restrict__ XU,
                                                   const _Float16* __restrict__ XI,
                                                   float* __restrict__ su, float* __restrict__ qu,
                                                   float* __restrict__ si, float* __restrict__ qi) {
  int rel = blockIdx.x >> 9;  // grid = 1024
  int blk = blockIdx.x & 511;
  const _Float16* X = rel ? XI : XU;
  float* sums = rel ? si : su;
  float* sqs = rel ? qi : qu;
  int c = threadIdx.x;
  float s = 0.f, q = 0.f;
  for (int r = blk; r < NN; r += 512) {
    float v = (float)X[(size_t)r * HF + c];
    s += v;
    q += v * v;
  }
  atomicAdd(&sums[c], s);
  atomicAdd(&sqs[c], q);
}

extern "C" void kernel_launch(void* const* d_in, const int* in_sizes, int n_in,
                              void* d_out, int out_size, void* d_ws, size_t ws_size,
                              hipStream_t stream) {
  (void)in_sizes; (void)n_in; (void)out_size; (void)ws_size;
  const float* x_user = (const float*)d_in[0];
  const float* x_item = (const float*)d_in[1];
  const int* ui_src = (const int*)d_in[2];
  const int* ui_dst = (const int*)d_in[3];
  const int* iu_src = (const int*)d_in[4];
  const int* iu_dst = (const int*)d_in[5];
  const float *Wp[4], *alp[4], *arp[4], *bp[4];
  for (int l = 0; l < 4; ++l) {
    Wp[l]  = (const float*)d_in[6 + 4 * l];
    alp[l] = (const float*)d_in[7 + 4 * l];
    arp[l] = (const float*)d_in[8 + 4 * l];
    bp[l]  = (const float*)d_in[9 + 4 * l];
  }
  const float* bng = (const float*)d_in[22];
  const float* bnb = (const float*)d_in[23];

  char* w = (char*)d_ws;
  auto alloc = [&](size_t bytes) -> void* {
    void* p = (void*)w;
    w += (bytes + 255) & ~(size_t)255;
    return p;
  };
  _Float16* XU16 = (_Float16*)alloc((size_t)NN * 128 * 2);
  _Float16* XI16 = (_Float16*)alloc((size_t)NN * 128 * 2);
  _Float16* Z0 = (_Float16*)alloc((size_t)NN * HF * 2);
  _Float16* Z1 = (_Float16*)alloc((size_t)NN * HF * 2);
  _Float16* RAW16U = (_Float16*)alloc((size_t)NN * HF * 2);
  _Float16* RAW16I = (_Float16*)alloc((size_t)NN * HF * 2);
  float* EL0 = (float*)alloc((size_t)NN * 4 * 4);
  float* ER0 = (float*)alloc((size_t)NN * 4 * 4);
  float* EL1 = (float*)alloc((size_t)NN * 4 * 4);
  float* ER1 = (float*)alloc((size_t)NN * 4 * 4);
  _Float16* WT = (_Float16*)alloc((size_t)8 * 65536 * 2);
  float* ATTN = (float*)alloc((size_t)8 * 1024 * 4);   // [l*2+r][256][4]
  float* SSU = (float*)alloc((size_t)512 * 4);
  float* SSI = (float*)alloc((size_t)512 * 4);
  int* rp_ui = (int*)alloc((size_t)(NN + 1) * 4);
  int* rp_iu = (int*)alloc((size_t)(NN + 1) * 4);
  int* csrc_ui = (int*)alloc((size_t)NE * 4);
  int* csrc_iu = (int*)alloc((size_t)NE * 4);
  int* counts = (int*)alloc((size_t)4 * NN * 4);  // counts_ui | counts_iu | fill_ui | fill_iu
  int* bsum_ui = (int*)alloc((size_t)64 * 4);
  int* bsum_iu = (int*)alloc((size_t)64 * 4);
  float* stats = (float*)alloc((size_t)6 * 512 * 4);

  int* counts_ui = counts;
  int* counts_iu = counts + NN;
  int* fill_ui = counts + 2 * NN;
  int* fill_iu = counts + 3 * NN;

  hipMemsetAsync(counts, 0, (size_t)4 * NN * 4, stream);
  hipMemsetAsync(stats, 0, (size_t)6 * 512 * 4, stream);

  // input conversion (one dispatch)
  int n4 = NN * 128 / 4;
  k_tofp16_2<<<(2 * n4 + 255) / 256, 256, 0, stream>>>(x_user, x_item, XU16, XI16, n4);

  // all weight transposes (one dispatch)
  TArgs ta;
  int cum = 0;
  for (int l = 0; l < 4; ++l) {
    int K = (l == 0) ? 128 : 256;
    for (int r = 0; r < 2; ++r) {
      int s = l * 2 + r;
      ta.W[s] = Wp[l] + (size_t)r * K * HF;
      ta.dst[s] = WT + (size_t)s * 65536;
      ta.K[s] = K;
      ta.cum[s] = cum;
      cum += K * 256;
    }
  }
  ta.cum[8] = cum;
  k_transpose_all<<<(cum + 255) / 256, 256, 0, stream>>>(ta);

  // all W.ar attn tables (one dispatch)
  k_makeattn_all<<<(8 * 256 * 4 + 255) / 256, 256, 0, stream>>>(
      Wp[0], Wp[1], Wp[2], Wp[3], arp[0], arp[1], arp[2], arp[3], ATTN);

  // CSR build (both relations per dispatch)
  int egrid2 = (2 * NE + 255) / 256;
  int nscan = (NN + 1023) / 1024;
  k_hist2<<<egrid2, 256, 0, stream>>>(ui_dst, iu_dst, counts_ui, counts_iu);
  k_scan1_2<<<2 * nscan, 1024, 0, stream>>>(counts_ui, counts_iu, rp_ui, rp_iu, bsum_ui, bsum_iu, nscan);
  k_scan2_2<<<1, 128, 0, stream>>>(bsum_ui, bsum_iu, nscan);
  k_scan3_2<<<2 * nscan, 1024, 0, stream>>>(rp_ui, rp_iu, bsum_ui, bsum_iu, nscan);
  k_scatter2<<<egrid2, 256, 0, stream>>>(ui_src, ui_dst, iu_src, iu_dst, rp_ui, rp_iu,
                                         fill_ui, fill_iu, csrc_ui, csrc_iu);

  int agrid = (NN + 3) / 4;
  int mgrid = (NN + 63) / 64;
  float* out_user = (float*)d_out;
  float* out_item = (float*)d_out + (size_t)NN * HF;

  for (int l = 0; l < 4; ++l) {
    int K = (l == 0) ? 128 : 256;
    int mode = (l == 0) ? 0 : ((l == 3) ? 2 : 1);
    const _Float16* Au = (l == 0) ? XU16 : RAW16U;
    const _Float16* Ai = (l == 0) ? XI16 : RAW16I;
    const float* war0 = ATTN + (size_t)(l * 2 + 0) * 1024;
    const float* war1 = ATTN + (size_t)(l * 2 + 1) * 1024;

    if (l > 0) {
      const float* su = stats + (size_t)((l - 1) * 2 + 0) * 512;
      const float* si = stats + (size_t)((l - 1) * 2 + 1) * 512;
      k_bnfinal<<<2, 256, 0, stream>>>(su, su + 256, si, si + 256,
                                       bng + (size_t)((l - 1) * 2 + 0) * 256,
                                       bnb + (size_t)((l - 1) * 2 + 0) * 256,
                                       bng + (size_t)((l - 1) * 2 + 1) * 256,
                                       bnb + (size_t)((l - 1) * 2 + 1) * 256,
                                       SSU, SSI);
    }

    // er0 = BN(hi) . (W0.ar0), er1 = BN(hu) . (W1.ar1)   (one dispatch)
    k_gemv_er2<<<2 * agrid, 256, 0, stream>>>(Ai, Au, war0, war1, ER0, ER1, SSI, SSU, K, mode);

    // GEMM pair: Z0 = BN(hu)@W0 (+el0), Z1 = BN(hi)@W1 (+el1)
    GArgs ga;
    ga.A0 = Au; ga.A1 = Ai;
    ga.Wt0 = WT + (size_t)(l * 2 + 0) * 65536;
    ga.Wt1 = WT + (size_t)(l * 2 + 1) * 65536;
    ga.Z0 = Z0; ga.Z1 = Z1;
    ga.al0 = alp[l] + 0; ga.al1 = alp[l] + 256;
    ga.EL0 = EL0; ga.EL1 = EL1;
    ga.ssu = SSU; ga.ssi = SSI;
    ga.M = NN; ga.K = K; ga.mode = mode;
    k_gemm3<<<2 * mgrid, 256, 0, stream>>>(ga);

    // aggregation pair: u->i (dst items, Z0) and i->u (dst users, Z1)
    if (l < 3)
      k_agg2<_Float16><<<2 * agrid, 256, 0, stream>>>(
          rp_ui, csrc_ui, EL0, ER0, Z0, bp[l] + 0, RAW16I,
          rp_iu, csrc_iu, EL1, ER1, Z1, bp[l] + 256, RAW16U);
    else
      k_agg2<float><<<2 * agrid, 256, 0, stream>>>(
          rp_ui, csrc_ui, EL0, ER0, Z0, bp[l] + 0, out_item,
          rp_iu, csrc_iu, EL1, ER1, Z1, bp[l] + 256, out_user);

    if (l < 3) {
      float* su = stats + (size_t)(l * 2 + 0) * 512;
      float* si = stats + (size_t)(l * 2 + 1) * 512;
      k_bn_stats2<<<1024, 256, 0, stream>>>(RAW16U, RAW16I, su, su + 256, si, si + 256);
    }
  }
}

// Round 10
// 1184.853 us; speedup vs baseline: 1.2226x; 1.0502x over previous
//
#include <hip/hip_runtime.h>
#include <hip/hip_bf16.h>
#include <type_traits>

#define NN 50000     // nodes per side (users == items == 50000)
#define NE 600000    // edges per relation
#define HF 256       // hidden features

typedef float f32x4 __attribute__((ext_vector_type(4)));
typedef _Float16 f16x8 __attribute__((ext_vector_type(8)));
typedef _Float16 f16x4 __attribute__((ext_vector_type(4)));

__device__ __forceinline__ float actf(float v, int mode) {
  if (mode == 1) return v >= 0.f ? v : 0.01f * v;
  if (mode == 2) return tanhf(v);
  return v;
}

// ---------- fp32 -> fp16 convert, both inputs in one dispatch ----------
__global__ __launch_bounds__(256) void k_tofp16_2(const float* __restrict__ A,
                                                  const float* __restrict__ B,
                                                  _Float16* __restrict__ OA,
                                                  _Float16* __restrict__ OB, int n4) {
  int i = blockIdx.x * 256 + threadIdx.x;
  const float* X = (i < n4) ? A : B;
  _Float16* Y = (i < n4) ? OA : OB;
  int j = (i < n4) ? i : i - n4;
  if (j < n4) {
    float4 v = reinterpret_cast<const float4*>(X)[j];
    f16x4 o = {(_Float16)v.x, (_Float16)v.y, (_Float16)v.z, (_Float16)v.w};
    reinterpret_cast<f16x4*>(Y)[j] = o;
  }
}

// ---------- all 8 W[K][256] -> Wt[256][K] transposes in one dispatch ----------
struct TArgs {
  const float* W[8];
  _Float16* dst[8];
  int K[8];
  int cum[9];
};
__global__ __launch_bounds__(256) void k_transpose_all(TArgs t) {
  int idx = blockIdx.x * 256 + threadIdx.x;
#pragma unroll
  for (int s = 0; s < 8; ++s) {
    if (idx >= t.cum[s] && idx < t.cum[s + 1]) {
      int local = idx - t.cum[s];
      int K = t.K[s];
      int k = local >> 8;
      int n = local & 255;
      t.dst[s][(size_t)n * K + k] = (_Float16)t.W[s][local];
    }
  }
}

// ---------- all W.ar attn tables in one dispatch ----------
__global__ __launch_bounds__(256) void k_makeattn_all(
    const float* __restrict__ W1, const float* __restrict__ W2,
    const float* __restrict__ W3, const float* __restrict__ W4,
    const float* __restrict__ ar1, const float* __restrict__ ar2,
    const float* __restrict__ ar3, const float* __restrict__ ar4,
    float* __restrict__ out) {
  int idx = blockIdx.x * 256 + threadIdx.x;
  if (idx >= 8 * 256 * 4) return;
  int h = idx & 3;
  int k = (idx >> 2) & 255;
  int s = idx >> 10;  // l*2+r
  int l = s >> 1, r = s & 1;
  int K = (l == 0) ? 128 : 256;
  if (k >= K) return;
  const float* W = (l == 0 ? W1 : l == 1 ? W2 : l == 2 ? W3 : W4) + (size_t)r * K * 256;
  const float* a = (l == 0 ? ar1 : l == 1 ? ar2 : l == 2 ? ar3 : ar4) + r * 256 + h * 64;
  const float* wrow = W + (size_t)k * 256 + h * 64;
  float sum = 0.f;
#pragma unroll 8
  for (int d = 0; d < 64; ++d) sum += wrow[d] * a[d];
  out[s * 1024 + k * 4 + h] = sum;
}

// ---------- BN finalize: scale/shift per column, both sides (grid = 2 blocks) ----------
__global__ __launch_bounds__(256) void k_bnfinal(
    const float* __restrict__ su, const float* __restrict__ qu,
    const float* __restrict__ si, const float* __restrict__ qi,
    const float* __restrict__ gu, const float* __restrict__ bu,
    const float* __restrict__ gi, const float* __restrict__ bi,
    float* __restrict__ ssu, float* __restrict__ ssi) {
  int side = blockIdx.x;
  const float* sums = side ? si : su;
  const float* sqs = side ? qi : qu;
  const float* g = side ? gi : gu;
  const float* bt = side ? bi : bu;
  float* ss = side ? ssi : ssu;
  int c = threadIdx.x;
  const float invN = 1.0f / NN;
  float mu = sums[c] * invN;
  float var = sqs[c] * invN - mu * mu;
  float sc = rsqrtf(var + 1e-5f) * g[c];
  ss[c] = sc;
  ss[256 + c] = bt[c] - mu * sc;
}

// ---------- er GEMV, both relations in one dispatch; inline BN+act ----------
__global__ __launch_bounds__(256) void k_gemv_er2(const _Float16* __restrict__ Xi,
                                                  const _Float16* __restrict__ Xu,
                                                  const float* __restrict__ war0,
                                                  const float* __restrict__ war1,
                                                  float* __restrict__ ER0, float* __restrict__ ER1,
                                                  const float* __restrict__ ssi,
                                                  const float* __restrict__ ssu,
                                                  int K, int mode) {
  int nb = (NN + 3) / 4;
  int rel = blockIdx.x >= nb;
  int bid = rel ? blockIdx.x - nb : blockIdx.x;
  const _Float16* X = rel ? Xu : Xi;
  const float* wa = rel ? war1 : war0;
  const float* ss = rel ? ssu : ssi;
  float* out = rel ? ER1 : ER0;
  int wid = bid * 4 + (threadIdx.x >> 6);
  if (wid >= NN) return;
  int lane = threadIdx.x & 63;
  float p0 = 0.f, p1 = 0.f, p2 = 0.f, p3 = 0.f;
  int k0 = lane * 4;
  if (k0 < K) {
    f16x4 x = *reinterpret_cast<const f16x4*>(X + (size_t)wid * K + k0);
    float xv[4] = {(float)x.x, (float)x.y, (float)x.z, (float)x.w};
    if (mode) {
      float4 sc = *reinterpret_cast<const float4*>(ss + k0);
      float4 sh = *reinterpret_cast<const float4*>(ss + 256 + k0);
      xv[0] = actf(xv[0] * sc.x + sh.x, mode);
      xv[1] = actf(xv[1] * sc.y + sh.y, mode);
      xv[2] = actf(xv[2] * sc.z + sh.z, mode);
      xv[3] = actf(xv[3] * sc.w + sh.w, mode);
    }
#pragma unroll
    for (int j = 0; j < 4; ++j) {
      float4 wv = *reinterpret_cast<const float4*>(wa + (k0 + j) * 4);
      p0 += xv[j] * wv.x; p1 += xv[j] * wv.y; p2 += xv[j] * wv.z; p3 += xv[j] * wv.w;
    }
  }
#pragma unroll
  for (int off = 32; off > 0; off >>= 1) {
    p0 += __shfl_down(p0, off); p1 += __shfl_down(p1, off);
    p2 += __shfl_down(p2, off); p3 += __shfl_down(p3, off);
  }
  if (lane == 0)
    *reinterpret_cast<float4*>(out + (size_t)wid * 4) = (float4){p0, p1, p2, p3};
}

// ---------- GEMM v4: LDS-staged A (global_load_lds + XOR swizzle), dbuf, fused BN + el ----------
struct GArgs {
  const _Float16* A0; const _Float16* A1;     // raw inputs (pre-BN for mode>0)
  const _Float16* Wt0; const _Float16* Wt1;
  _Float16* Z0; _Float16* Z1;
  const float* al0; const float* al1;
  float* EL0; float* EL1;
  const float* ssu; const float* ssi;         // [scale 256 | shift 256] per side
  int M, K, mode;                             // mode: 0 none, 1 leaky0.01, 2 tanh
};

__global__ __launch_bounds__(256) void k_gemm4(GArgs ga) {
  __shared__ _Float16 As[2][128 * 64];   // 2 x 16 KB double buffer
  const int nrow = (NN + 127) / 128;     // 391
  int g1 = 2 * nrow;
  int side = blockIdx.x >= g1;
  int rem = side ? blockIdx.x - g1 : blockIdx.x;
  int coltile = rem / nrow;              // 0 or 1
  int rowblk = rem - coltile * nrow;
  const _Float16* A = side ? ga.A1 : ga.A0;
  const _Float16* Wt = side ? ga.Wt1 : ga.Wt0;
  _Float16* Z = side ? ga.Z1 : ga.Z0;
  const float* al = side ? ga.al1 : ga.al0;
  float* EL = side ? ga.EL1 : ga.EL0;
  const float* ss = side ? ga.ssi : ga.ssu;
  const int K = ga.K, M = ga.M, mode = ga.mode;
  int row0 = rowblk * 128;
  int wave = threadIdx.x >> 6;
  int lane = threadIdx.x & 63;
  int wr = wave >> 1, wc = wave & 1;     // wave tile: rows wr*64.., cols wc*64..
  int lr = lane & 15, kg = lane >> 4;
  int head = coltile * 2 + wc;           // each wave's 64 cols == one head
  int col0 = head * 64;

  // stage A tile [row0..row0+128) x [k0..k0+64) into As[buf], source pre-swizzled
  auto stage = [&](int buf, int k0) {
#pragma unroll
    for (int j = 0; j < 4; ++j) {
      int Lb = j * 4096 + wave * 1024;          // wave-uniform LDS byte base
      int L = Lb + lane * 16;                   // this lane's linear slot
      int r = L >> 7;                           // row in tile
      int kb = (L & 127) ^ ((r & 7) << 4);      // pre-swizzled source column byte
      int rg = row0 + r; rg = rg < M ? rg : M - 1;
      const char* gsrc = (const char*)A + ((size_t)rg * K + k0) * 2 + kb;
      char* ldst = (char*)(&As[buf][0]) + Lb;
      __builtin_amdgcn_global_load_lds(
          (const __attribute__((address_space(1))) unsigned int*)gsrc,
          (__attribute__((address_space(3))) unsigned int*)ldst, 16, 0, 0);
    }
  };

  f32x4 acc[4][4];
#pragma unroll
  for (int i = 0; i < 4; ++i)
#pragma unroll
    for (int j = 0; j < 4; ++j) acc[i][j] = (f32x4){0.f, 0.f, 0.f, 0.f};

  int nt = K >> 6;   // BK = 64
  stage(0, 0);
  __syncthreads();
  for (int t = 0; t < nt; ++t) {
    if (t + 1 < nt) stage((t + 1) & 1, (t + 1) * 64);
    const char* abuf = (const char*)(&As[t & 1][0]);
#pragma unroll
    for (int s = 0; s < 2; ++s) {
      int kk = t * 64 + s * 32 + kg * 8;
      float sc[8], sh[8];
      if (mode) {
        float4 a0 = *reinterpret_cast<const float4*>(ss + kk);
        float4 a1 = *reinterpret_cast<const float4*>(ss + kk + 4);
        float4 b0 = *reinterpret_cast<const float4*>(ss + 256 + kk);
        float4 b1 = *reinterpret_cast<const float4*>(ss + 256 + kk + 4);
        sc[0] = a0.x; sc[1] = a0.y; sc[2] = a0.z; sc[3] = a0.w;
        sc[4] = a1.x; sc[5] = a1.y; sc[6] = a1.z; sc[7] = a1.w;
        sh[0] = b0.x; sh[1] = b0.y; sh[2] = b0.z; sh[3] = b0.w;
        sh[4] = b1.x; sh[5] = b1.y; sh[6] = b1.z; sh[7] = b1.w;
      }
      f16x8 af[4], bfr[4];
#pragma unroll
      for (int mt = 0; mt < 4; ++mt) {
        int r = wr * 64 + mt * 16 + lr;
        int cb = ((s << 6) | (kg << 4)) ^ ((r & 7) << 4);   // swizzled read
        f16x8 raw = *reinterpret_cast<const f16x8*>(abuf + r * 128 + cb);
        if (mode) {
          f16x8 o;
#pragma unroll
          for (int j = 0; j < 8; ++j)
            o[j] = (_Float16)actf((float)raw[j] * sc[j] + sh[j], mode);
          af[mt] = o;
        } else {
          af[mt] = raw;
        }
      }
#pragma unroll
      for (int ct = 0; ct < 4; ++ct) {
        int c = col0 + ct * 16 + lr;
        bfr[ct] = *reinterpret_cast<const f16x8*>(Wt + (size_t)c * K + kk);
      }
#pragma unroll
      for (int mt = 0; mt < 4; ++mt)
#pragma unroll
        for (int ct = 0; ct < 4; ++ct)
          acc[mt][ct] = __builtin_amdgcn_mfma_f32_16x16x32_f16(af[mt], bfr[ct], acc[mt][ct], 0, 0, 0);
    }
    __syncthreads();
  }

  // C-write: col = lane&15, row = (lane>>4)*4 + reg
#pragma unroll
  for (int mt = 0; mt < 4; ++mt) {
#pragma unroll
    for (int r = 0; r < 4; ++r) {
      int row = row0 + wr * 64 + mt * 16 + kg * 4 + r;
      if (row < M) {
#pragma unroll
        for (int ct = 0; ct < 4; ++ct) {
          int col = col0 + ct * 16 + lr;
          Z[(size_t)row * HF + col] = (_Float16)acc[mt][ct][r];
        }
      }
    }
  }
  // fused el epilogue: this wave's 64 cols == head's 64 dims
  float al4[4];
#pragma unroll
  for (int ct = 0; ct < 4; ++ct) al4[ct] = al[col0 + ct * 16 + lr];
#pragma unroll
  for (int mt = 0; mt < 4; ++mt) {
#pragma unroll
    for (int r = 0; r < 4; ++r) {
      float p = acc[mt][0][r] * al4[0] + acc[mt][1][r] * al4[1] +
                acc[mt][2][r] * al4[2] + acc[mt][3][r] * al4[3];
#pragma unroll
      for (int off = 1; off < 16; off <<= 1) p += __shfl_xor(p, off);
      int row = row0 + wr * 64 + mt * 16 + kg * 4 + r;
      if (lr == 0 && row < M) EL[(size_t)row * 4 + head] = p;
    }
  }
}

// ---------- CSR build (both relations per dispatch) ----------
__global__ __launch_bounds__(256) void k_hist2(const int* __restrict__ d0, const int* __restrict__ d1,
                                               int* __restrict__ c0, int* __restrict__ c1) {
  int t = blockIdx.x * 256 + threadIdx.x;
  if (t < NE) atomicAdd(&c0[d0[t]], 1);
  else if (t < 2 * NE) atomicAdd(&c1[d1[t - NE]], 1);
}

__global__ __launch_bounds__(1024) void k_scan1_2(const int* __restrict__ c0, const int* __restrict__ c1,
                                                  int* __restrict__ rp0, int* __restrict__ rp1,
                                                  int* __restrict__ b0, int* __restrict__ b1, int nscan) {
  __shared__ int tmp[1024];
  int rel = blockIdx.x >= nscan;
  int blk = rel ? blockIdx.x - nscan : blockIdx.x;
  const int* counts = rel ? c1 : c0;
  int* rp = rel ? rp1 : rp0;
  int* bsum = rel ? b1 : b0;
  int i = blk * 1024 + threadIdx.x;
  int v = (i < NN) ? counts[i] : 0;
  tmp[threadIdx.x] = v;
  __syncthreads();
  for (int off = 1; off < 1024; off <<= 1) {
    int t = (threadIdx.x >= off) ? tmp[threadIdx.x - off] : 0;
    __syncthreads();
    tmp[threadIdx.x] += t;
    __syncthreads();
  }
  if (i < NN) rp[i] = tmp[threadIdx.x] - v;  // block-local exclusive
  if (threadIdx.x == 1023) bsum[blk] = tmp[1023];
}

__global__ __launch_bounds__(128) void k_scan2_2(int* __restrict__ b0, int* __restrict__ b1, int nb) {
  int rel = threadIdx.x >> 6;
  int l = threadIdx.x & 63;
  int* bsum = rel ? b1 : b0;
  int orig = (l < nb) ? bsum[l] : 0;
  int v = orig;
#pragma unroll
  for (int off = 1; off < 64; off <<= 1) {
    int t = __shfl_up(v, off);
    if (l >= off) v += t;
  }
  if (l < nb) bsum[l] = v - orig;  // exclusive
}

__global__ __launch_bounds__(1024) void k_scan3_2(int* __restrict__ rp0, int* __restrict__ rp1,
                                                  const int* __restrict__ b0, const int* __restrict__ b1,
                                                  int nscan) {
  int rel = blockIdx.x >= nscan;
  int blk = rel ? blockIdx.x - nscan : blockIdx.x;
  int* rp = rel ? rp1 : rp0;
  const int* bsum = rel ? b1 : b0;
  int i = blk * 1024 + threadIdx.x;
  if (i < NN) rp[i] += bsum[blk];
  if (i == 0) rp[NN] = NE;
}

__global__ __launch_bounds__(256) void k_scatter2(
    const int* __restrict__ s0, const int* __restrict__ d0,
    const int* __restrict__ s1, const int* __restrict__ d1,
    const int* __restrict__ rp0, const int* __restrict__ rp1,
    int* __restrict__ f0, int* __restrict__ f1,
    int* __restrict__ cs0, int* __restrict__ cs1) {
  int t = blockIdx.x * 256 + threadIdx.x;
  if (t < NE) {
    int d = d0[t];
    int pos = rp0[d] + atomicAdd(&f0[d], 1);
    cs0[pos] = s0[t];
  } else if (t < 2 * NE) {
    int e = t - NE;
    int d = d1[e];
    int pos = rp1[d] + atomicAdd(&f1[d], 1);
    cs1[pos] = s1[e];
  }
}

__device__ __forceinline__ float pick_h(float4 v, int h) {
  float r = v.x;
  r = (h == 1) ? v.y : r;
  r = (h == 2) ? v.z : r;
  r = (h == 3) ? v.w : r;
  return r;
}

// ---------- fused GAT aggregation, both relations per dispatch ----------
template <typename OT>
__global__ __launch_bounds__(256) void k_agg2(
    const int* __restrict__ rpA, const int* __restrict__ csA,
    const float* __restrict__ elA, const float* __restrict__ erA,
    const _Float16* __restrict__ ZA, const float* __restrict__ bA, OT* __restrict__ oA,
    const int* __restrict__ rpB, const int* __restrict__ csB,
    const float* __restrict__ elB, const float* __restrict__ erB,
    const _Float16* __restrict__ ZB, const float* __restrict__ bB, OT* __restrict__ oB) {
  __shared__ float exs[4][256];
  __shared__ int ssrc[4][64];
  int nb = (NN + 3) / 4;
  int rel = blockIdx.x >= nb;
  int bid = rel ? blockIdx.x - nb : blockIdx.x;
  const int* rp = rel ? rpB : rpA;
  const int* csrc = rel ? csB : csA;
  const float* el = rel ? elB : elA;
  const float* er = rel ? erB : erA;
  const _Float16* Z = rel ? ZB : ZA;
  const float* bias = rel ? bB : bA;
  OT* out = rel ? oB : oA;

  int wv = threadIdx.x >> 6;
  int wid = bid * 4 + wv;
  if (wid >= NN) return;
  int lane = threadIdx.x & 63;
  int half = lane >> 5, l5 = lane & 31;
  int c0 = l5 * 8;      // 8 cols per lane (halves cover full row)
  int h = l5 >> 3;      // head for cols c0..c0+7
  int beg = rp[wid], end = rp[wid + 1];
  int deg = end - beg;

  if (deg == 0) {
    if (half == 0) {
      float4 b0 = *reinterpret_cast<const float4*>(bias + c0);
      float4 b1 = *reinterpret_cast<const float4*>(bias + c0 + 4);
      if constexpr (std::is_same<OT, float>::value) {
        float4* op = reinterpret_cast<float4*>(out + (size_t)wid * HF + c0);
        op[0] = b0; op[1] = b1;
      } else {
        f16x8 o = {(_Float16)b0.x, (_Float16)b0.y, (_Float16)b0.z, (_Float16)b0.w,
                   (_Float16)b1.x, (_Float16)b1.y, (_Float16)b1.z, (_Float16)b1.w};
        *reinterpret_cast<f16x8*>(out + (size_t)wid * HF + c0) = o;
      }
    }
    return;
  }

  if (deg <= 64) {
    // ---- pass A: lane i owns edge i ----
    int s = 0;
    float4 x = {-1e30f, -1e30f, -1e30f, -1e30f};
    float4 b = *reinterpret_cast<const float4*>(er + (size_t)wid * 4);
    if (lane < deg) {
      s = csrc[beg + lane];
      float4 a = reinterpret_cast<const float4*>(el)[s];
      x.x = a.x + b.x; x.x = x.x >= 0.f ? x.x : 0.2f * x.x;
      x.y = a.y + b.y; x.y = x.y >= 0.f ? x.y : 0.2f * x.y;
      x.z = a.z + b.z; x.z = x.z >= 0.f ? x.z : 0.2f * x.z;
      x.w = a.w + b.w; x.w = x.w >= 0.f ? x.w : 0.2f * x.w;
    }
    float4 m = x;
#pragma unroll
    for (int off = 32; off > 0; off >>= 1) {
      m.x = fmaxf(m.x, __shfl_xor(m.x, off));
      m.y = fmaxf(m.y, __shfl_xor(m.y, off));
      m.z = fmaxf(m.z, __shfl_xor(m.z, off));
      m.w = fmaxf(m.w, __shfl_xor(m.w, off));
    }
    float4 ex = {0.f, 0.f, 0.f, 0.f};
    if (lane < deg) {
      ex.x = __expf(x.x - m.x);
      ex.y = __expf(x.y - m.y);
      ex.z = __expf(x.z - m.z);
      ex.w = __expf(x.w - m.w);
    }
    float4 sm = ex;
#pragma unroll
    for (int off = 32; off > 0; off >>= 1) {
      sm.x += __shfl_xor(sm.x, off);
      sm.y += __shfl_xor(sm.y, off);
      sm.z += __shfl_xor(sm.z, off);
      sm.w += __shfl_xor(sm.w, off);
    }
    float inv = 1.0f / pick_h(sm, h);
    if (lane < deg) {
      *reinterpret_cast<float4*>(&exs[wv][lane * 4]) = ex;
      ssrc[wv][lane] = s;
    }
    // ---- pass B: halves own alternate edges, 4-group unroll -> 8 gathers in flight ----
    float a8[8] = {0.f, 0.f, 0.f, 0.f, 0.f, 0.f, 0.f, 0.f};
    int j = half;
#define AGG_STEP(J)                                                        \
    {                                                                      \
      int sj = ssrc[wv][(J)];                                              \
      float wj = exs[wv][(J) * 4 + h];                                     \
      f16x8 z = *reinterpret_cast<const f16x8*>(Z + (size_t)sj * HF + c0); \
      _Pragma("unroll")                                                    \
      for (int q = 0; q < 8; ++q) a8[q] += wj * (float)z[q];               \
    }
    for (; j + 6 < deg; j += 8) {
      AGG_STEP(j); AGG_STEP(j + 2); AGG_STEP(j + 4); AGG_STEP(j + 6);
    }
    for (; j < deg; j += 2) { AGG_STEP(j); }
#undef AGG_STEP
#pragma unroll
    for (int q = 0; q < 8; ++q) a8[q] += __shfl_xor(a8[q], 32);
    if (half == 0) {
      float4 b0 = *reinterpret_cast<const float4*>(bias + c0);
      float4 b1 = *reinterpret_cast<const float4*>(bias + c0 + 4);
      float r0 = a8[0] * inv + b0.x, r1 = a8[1] * inv + b0.y;
      float r2 = a8[2] * inv + b0.z, r3 = a8[3] * inv + b0.w;
      float r4 = a8[4] * inv + b1.x, r5 = a8[5] * inv + b1.y;
      float r6 = a8[6] * inv + b1.z, r7 = a8[7] * inv + b1.w;
      if constexpr (std::is_same<OT, float>::value) {
        float4* op = reinterpret_cast<float4*>(out + (size_t)wid * HF + c0);
        op[0] = (float4){r0, r1, r2, r3};
        op[1] = (float4){r4, r5, r6, r7};
      } else {
        f16x8 o = {(_Float16)r0, (_Float16)r1, (_Float16)r2, (_Float16)r3,
                   (_Float16)r4, (_Float16)r5, (_Float16)r6, (_Float16)r7};
        *reinterpret_cast<f16x8*>(out + (size_t)wid * HF + c0) = o;
      }
    }
    return;
  }

  // ---- rare fallback (deg > 64): uniform two-pass, full-wave f16x4 mapping ----
  {
    int c4 = lane * 4;
    int h4 = lane >> 4;
    float4 b = *reinterpret_cast<const float4*>(er + (size_t)wid * 4);
    float4 m = {-1e30f, -1e30f, -1e30f, -1e30f};
    for (int e = beg; e < end; ++e) {
      int s = csrc[e];
      float4 a = reinterpret_cast<const float4*>(el)[s];
      float4 x;
      x.x = a.x + b.x; x.x = x.x >= 0.f ? x.x : 0.2f * x.x;
      x.y = a.y + b.y; x.y = x.y >= 0.f ? x.y : 0.2f * x.y;
      x.z = a.z + b.z; x.z = x.z >= 0.f ? x.z : 0.2f * x.z;
      x.w = a.w + b.w; x.w = x.w >= 0.f ? x.w : 0.2f * x.w;
      m.x = fmaxf(m.x, x.x); m.y = fmaxf(m.y, x.y);
      m.z = fmaxf(m.z, x.z); m.w = fmaxf(m.w, x.w);
    }
    float4 sm = {0.f, 0.f, 0.f, 0.f};
    float4 acc = {0.f, 0.f, 0.f, 0.f};
    for (int e = beg; e < end; ++e) {
      int s = csrc[e];
      float4 a = reinterpret_cast<const float4*>(el)[s];
      float4 x;
      x.x = a.x + b.x; x.x = x.x >= 0.f ? x.x : 0.2f * x.x;
      x.y = a.y + b.y; x.y = x.y >= 0.f ? x.y : 0.2f * x.y;
      x.z = a.z + b.z; x.z = x.z >= 0.f ? x.z : 0.2f * x.z;
      x.w = a.w + b.w; x.w = x.w >= 0.f ? x.w : 0.2f * x.w;
      float4 exv;
      exv.x = __expf(x.x - m.x); exv.y = __expf(x.y - m.y);
      exv.z = __expf(x.z - m.z); exv.w = __expf(x.w - m.w);
      sm.x += exv.x; sm.y += exv.y; sm.z += exv.z; sm.w += exv.w;
      float w0 = pick_h(exv, h4);
      f16x4 z0 = *reinterpret_cast<const f16x4*>(Z + (size_t)s * HF + c4);
      acc.x += w0 * (float)z0.x;
      acc.y += w0 * (float)z0.y;
      acc.z += w0 * (float)z0.z;
      acc.w += w0 * (float)z0.w;
    }
    float inv = 1.0f / pick_h(sm, h4);
    float4 bv = *reinterpret_cast<const float4*>(bias + c4);
    float r0 = acc.x * inv + bv.x, r1 = acc.y * inv + bv.y;
    float r2 = acc.z * inv + bv.z, r3 = acc.w * inv + bv.w;
    if constexpr (std::is_same<OT, float>::value) {
      *reinterpret_cast<float4*>(out + (size_t)wid * HF + c4) = (float4){r0, r1, r2, r3};
    } else {
      f16x4 o = {(_Float16)r0, (_Float16)r1, (_Float16)r2, (_Float16)r3};
      *reinterpret_cast<f16x4*>(out + (size_t)wid * HF + c4) = o;
    }
  }
}

// ---------- batchnorm stats, both sides per dispatch ----------
__global__ __launch_bounds__(256) void k_bn_stats2(const _Float16* __restrict__ XU,
                                                   const _Float16* __restrict__ XI,
                                                   float* __restrict__ su, float* __restrict__ qu,
                                                   float* __restrict__ si, float* __restrict__ qi) {
  int rel = blockIdx.x >> 9;  // grid = 1024
  int blk = blockIdx.x & 511;
  const _Float16* X = rel ? XI : XU;
  float* sums = rel ? si : su;
  float* sqs = rel ? qi : qu;
  int c = threadIdx.x;
  float s = 0.f, q = 0.f;
  for (int r = blk; r < NN; r += 512) {
    float v = (float)X[(size_t)r * HF + c];
    s += v;
    q += v * v;
  }
  atomicAdd(&sums[c], s);
  atomicAdd(&sqs[c], q);
}

extern "C" void kernel_launch(void* const* d_in, const int* in_sizes, int n_in,
                              void* d_out, int out_size, void* d_ws, size_t ws_size,
                              hipStream_t stream) {
  (void)in_sizes; (void)n_in; (void)out_size; (void)ws_size;
  const float* x_user = (const float*)d_in[0];
  const float* x_item = (const float*)d_in[1];
  const int* ui_src = (const int*)d_in[2];
  const int* ui_dst = (const int*)d_in[3];
  const int* iu_src = (const int*)d_in[4];
  const int* iu_dst = (const int*)d_in[5];
  const float *Wp[4], *alp[4], *arp[4], *bp[4];
  for (int l = 0; l < 4; ++l) {
    Wp[l]  = (const float*)d_in[6 + 4 * l];
    alp[l] = (const float*)d_in[7 + 4 * l];
    arp[l] = (const float*)d_in[8 + 4 * l];
    bp[l]  = (const float*)d_in[9 + 4 * l];
  }
  const float* bng = (const float*)d_in[22];
  const float* bnb = (const float*)d_in[23];

  char* w = (char*)d_ws;
  auto alloc = [&](size_t bytes) -> void* {
    void* p = (void*)w;
    w += (bytes + 255) & ~(size_t)255;
    return p;
  };
  _Float16* XU16 = (_Float16*)alloc((size_t)NN * 128 * 2);
  _Float16* XI16 = (_Float16*)alloc((size_t)NN * 128 * 2);
  _Float16* Z0 = (_Float16*)alloc((size_t)NN * HF * 2);
  _Float16* Z1 = (_Float16*)alloc((size_t)NN * HF * 2);
  _Float16* RAW16U = (_Float16*)alloc((size_t)NN * HF * 2);
  _Float16* RAW16I = (_Float16*)alloc((size_t)NN * HF * 2);
  float* EL0 = (float*)alloc((size_t)NN * 4 * 4);
  float* ER0 = (float*)alloc((size_t)NN * 4 * 4);
  float* EL1 = (float*)alloc((size_t)NN * 4 * 4);
  float* ER1 = (float*)alloc((size_t)NN * 4 * 4);
  _Float16* WT = (_Float16*)alloc((size_t)8 * 65536 * 2);
  float* ATTN = (float*)alloc((size_t)8 * 1024 * 4);   // [l*2+r][256][4]
  float* SSU = (float*)alloc((size_t)512 * 4);
  float* SSI = (float*)alloc((size_t)512 * 4);
  int* rp_ui = (int*)alloc((size_t)(NN + 1) * 4);
  int* rp_iu = (int*)alloc((size_t)(NN + 1) * 4);
  int* csrc_ui = (int*)alloc((size_t)NE * 4);
  int* csrc_iu = (int*)alloc((size_t)NE * 4);
  int* counts = (int*)alloc((size_t)4 * NN * 4);  // counts_ui | counts_iu | fill_ui | fill_iu
  int* bsum_ui = (int*)alloc((size_t)64 * 4);
  int* bsum_iu = (int*)alloc((size_t)64 * 4);
  float* stats = (float*)alloc((size_t)6 * 512 * 4);

  int* counts_ui = counts;
  int* counts_iu = counts + NN;
  int* fill_ui = counts + 2 * NN;
  int* fill_iu = counts + 3 * NN;

  hipMemsetAsync(counts, 0, (size_t)4 * NN * 4, stream);
  hipMemsetAsync(stats, 0, (size_t)6 * 512 * 4, stream);

  // input conversion (one dispatch)
  int n4 = NN * 128 / 4;
  k_tofp16_2<<<(2 * n4 + 255) / 256, 256, 0, stream>>>(x_user, x_item, XU16, XI16, n4);

  // all weight transposes (one dispatch)
  TArgs ta;
  int cum = 0;
  for (int l = 0; l < 4; ++l) {
    int K = (l == 0) ? 128 : 256;
    for (int r = 0; r < 2; ++r) {
      int s = l * 2 + r;
      ta.W[s] = Wp[l] + (size_t)r * K * HF;
      ta.dst[s] = WT + (size_t)s * 65536;
      ta.K[s] = K;
      ta.cum[s] = cum;
      cum += K * 256;
    }
  }
  ta.cum[8] = cum;
  k_transpose_all<<<(cum + 255) / 256, 256, 0, stream>>>(ta);

  // all W.ar attn tables (one dispatch)
  k_makeattn_all<<<(8 * 256 * 4 + 255) / 256, 256, 0, stream>>>(
      Wp[0], Wp[1], Wp[2], Wp[3], arp[0], arp[1], arp[2], arp[3], ATTN);

  // CSR build (both relations per dispatch)
  int egrid2 = (2 * NE + 255) / 256;
  int nscan = (NN + 1023) / 1024;
  k_hist2<<<egrid2, 256, 0, stream>>>(ui_dst, iu_dst, counts_ui, counts_iu);
  k_scan1_2<<<2 * nscan, 1024, 0, stream>>>(counts_ui, counts_iu, rp_ui, rp_iu, bsum_ui, bsum_iu, nscan);
  k_scan2_2<<<1, 128, 0, stream>>>(bsum_ui, bsum_iu, nscan);
  k_scan3_2<<<2 * nscan, 1024, 0, stream>>>(rp_ui, rp_iu, bsum_ui, bsum_iu, nscan);
  k_scatter2<<<egrid2, 256, 0, stream>>>(ui_src, ui_dst, iu_src, iu_dst, rp_ui, rp_iu,
                                         fill_ui, fill_iu, csrc_ui, csrc_iu);

  int agrid = (NN + 3) / 4;
  int nrow = (NN + 127) / 128;
  float* out_user = (float*)d_out;
  float* out_item = (float*)d_out + (size_t)NN * HF;

  for (int l = 0; l < 4; ++l) {
    int K = (l == 0) ? 128 : 256;
    int mode = (l == 0) ? 0 : ((l == 3) ? 2 : 1);
    const _Float16* Au = (l == 0) ? XU16 : RAW16U;
    const _Float16* Ai = (l == 0) ? XI16 : RAW16I;
    const float* war0 = ATTN + (size_t)(l * 2 + 0) * 1024;
    const float* war1 = ATTN + (size_t)(l * 2 + 1) * 1024;

    if (l > 0) {
      const float* su = stats + (size_t)((l - 1) * 2 + 0) * 512;
      const float* si = stats + (size_t)((l - 1) * 2 + 1) * 512;
      k_bnfinal<<<2, 256, 0, stream>>>(su, su + 256, si, si + 256,
                                       bng + (size_t)((l - 1) * 2 + 0) * 256,
                                       bnb + (size_t)((l - 1) * 2 + 0) * 256,
                                       bng + (size_t)((l - 1) * 2 + 1) * 256,
                                       bnb + (size_t)((l - 1) * 2 + 1) * 256,
                                       SSU, SSI);
    }

    // er0 = BN(hi) . (W0.ar0), er1 = BN(hu) . (W1.ar1)   (one dispatch)
    k_gemv_er2<<<2 * agrid, 256, 0, stream>>>(Ai, Au, war0, war1, ER0, ER1, SSI, SSU, K, mode);

    // GEMM pair: Z0 = BN(hu)@W0 (+el0), Z1 = BN(hi)@W1 (+el1)
    GArgs ga;
    ga.A0 = Au; ga.A1 = Ai;
    ga.Wt0 = WT + (size_t)(l * 2 + 0) * 65536;
    ga.Wt1 = WT + (size_t)(l * 2 + 1) * 65536;
    ga.Z0 = Z0; ga.Z1 = Z1;
    ga.al0 = alp[l] + 0; ga.al1 = alp[l] + 256;
    ga.EL0 = EL0; ga.EL1 = EL1;
    ga.ssu = SSU; ga.ssi = SSI;
    ga.M = NN; ga.K = K; ga.mode = mode;
    k_gemm4<<<4 * nrow, 256, 0, stream>>>(ga);

    // aggregation pair: u->i (dst items, Z0) and i->u (dst users, Z1)
    if (l < 3)
      k_agg2<_Float16><<<2 * agrid, 256, 0, stream>>>(
          rp_ui, csrc_ui, EL0, ER0, Z0, bp[l] + 0, RAW16I,
          rp_iu, csrc_iu, EL1, ER1, Z1, bp[l] + 256, RAW16U);
    else
      k_agg2<float><<<2 * agrid, 256, 0, stream>>>(
          rp_ui, csrc_ui, EL0, ER0, Z0, bp[l] + 0, out_item,
          rp_iu, csrc_iu, EL1, ER1, Z1, bp[l] + 256, out_user);

    if (l < 3) {
      float* su = stats + (size_t)(l * 2 + 0) * 512;
      float* si = stats + (size_t)(l * 2 + 1) * 512;
      k_bn_stats2<<<1024, 256, 0, stream>>>(RAW16U, RAW16I, su, su + 256, si, si + 256);
    }
  }
}

// Round 11
// 1048.482 us; speedup vs baseline: 1.3816x; 1.1301x over previous
//
#include <hip/hip_runtime.h>
#include <hip/hip_bf16.h>
#include <type_traits>

#define NN 50000     // nodes per side (users == items == 50000)
#define NE 600000    // edges per relation
#define HF 256       // hidden features

typedef float f32x4 __attribute__((ext_vector_type(4)));
typedef _Float16 f16x8 __attribute__((ext_vector_type(8)));
typedef _Float16 f16x4 __attribute__((ext_vector_type(4)));

// ---------- fp32 -> fp16 convert, both inputs in one dispatch ----------
__global__ __launch_bounds__(256) void k_tofp16_2(const float* __restrict__ A,
                                                  const float* __restrict__ B,
                                                  _Float16* __restrict__ OA,
                                                  _Float16* __restrict__ OB, int n4) {
  int i = blockIdx.x * 256 + threadIdx.x;
  const float* X = (i < n4) ? A : B;
  _Float16* Y = (i < n4) ? OA : OB;
  int j = (i < n4) ? i : i - n4;
  if (j < n4) {
    float4 v = reinterpret_cast<const float4*>(X)[j];
    f16x4 o = {(_Float16)v.x, (_Float16)v.y, (_Float16)v.z, (_Float16)v.w};
    reinterpret_cast<f16x4*>(Y)[j] = o;
  }
}

// ---------- all 8 W[K][256] -> Wt[256][K] transposes in one dispatch ----------
struct TArgs {
  const float* W[8];
  _Float16* dst[8];
  int K[8];
  int cum[9];
};
__global__ __launch_bounds__(256) void k_transpose_all(TArgs t) {
  int idx = blockIdx.x * 256 + threadIdx.x;
#pragma unroll
  for (int s = 0; s < 8; ++s) {
    if (idx >= t.cum[s] && idx < t.cum[s + 1]) {
      int local = idx - t.cum[s];
      int K = t.K[s];
      int k = local >> 8;
      int n = local & 255;
      t.dst[s][(size_t)n * K + k] = (_Float16)t.W[s][local];
    }
  }
}

// ---------- all W.ar attn tables in one dispatch ----------
__global__ __launch_bounds__(256) void k_makeattn_all(
    const float* __restrict__ W1, const float* __restrict__ W2,
    const float* __restrict__ W3, const float* __restrict__ W4,
    const float* __restrict__ ar1, const float* __restrict__ ar2,
    const float* __restrict__ ar3, const float* __restrict__ ar4,
    float* __restrict__ out) {
  int idx = blockIdx.x * 256 + threadIdx.x;
  if (idx >= 8 * 256 * 4) return;
  int h = idx & 3;
  int k = (idx >> 2) & 255;
  int s = idx >> 10;  // l*2+r
  int l = s >> 1, r = s & 1;
  int K = (l == 0) ? 128 : 256;
  if (k >= K) return;
  const float* W = (l == 0 ? W1 : l == 1 ? W2 : l == 2 ? W3 : W4) + (size_t)r * K * 256;
  const float* a = (l == 0 ? ar1 : l == 1 ? ar2 : l == 2 ? ar3 : ar4) + r * 256 + h * 64;
  const float* wrow = W + (size_t)k * 256 + h * 64;
  float sum = 0.f;
#pragma unroll 8
  for (int d = 0; d < 64; ++d) sum += wrow[d] * a[d];
  out[s * 1024 + k * 4 + h] = sum;
}

// ---------- er GEMV, both relations in one dispatch (A already post-BN) ----------
__global__ __launch_bounds__(256) void k_gemv_er2(const _Float16* __restrict__ Xi,
                                                  const _Float16* __restrict__ Xu,
                                                  const float* __restrict__ war0,
                                                  const float* __restrict__ war1,
                                                  float* __restrict__ ER0, float* __restrict__ ER1,
                                                  int K) {
  int nb = (NN + 3) / 4;
  int rel = blockIdx.x >= nb;
  int bid = rel ? blockIdx.x - nb : blockIdx.x;
  const _Float16* X = rel ? Xu : Xi;
  const float* wa = rel ? war1 : war0;
  float* out = rel ? ER1 : ER0;
  int wid = bid * 4 + (threadIdx.x >> 6);
  if (wid >= NN) return;
  int lane = threadIdx.x & 63;
  float p0 = 0.f, p1 = 0.f, p2 = 0.f, p3 = 0.f;
  int k0 = lane * 4;
  if (k0 < K) {
    f16x4 x = *reinterpret_cast<const f16x4*>(X + (size_t)wid * K + k0);
    float xv[4] = {(float)x.x, (float)x.y, (float)x.z, (float)x.w};
#pragma unroll
    for (int j = 0; j < 4; ++j) {
      float4 wv = *reinterpret_cast<const float4*>(wa + (k0 + j) * 4);
      p0 += xv[j] * wv.x; p1 += xv[j] * wv.y; p2 += xv[j] * wv.z; p3 += xv[j] * wv.w;
    }
  }
#pragma unroll
  for (int off = 32; off > 0; off >>= 1) {
    p0 += __shfl_down(p0, off); p1 += __shfl_down(p1, off);
    p2 += __shfl_down(p2, off); p3 += __shfl_down(p3, off);
  }
  if (lane == 0)
    *reinterpret_cast<float4*>(out + (size_t)wid * 4) = (float4){p0, p1, p2, p3};
}

// ---------- GEMM v5: pure MFMA, 64x256 block tile, LDS-staged A (swizzled), dbuf, fused el ----------
struct GArgs {
  const _Float16* A0; const _Float16* A1;     // post-BN activations
  const _Float16* Wt0; const _Float16* Wt1;
  _Float16* Z0; _Float16* Z1;
  const float* al0; const float* al1;
  float* EL0; float* EL1;
  int M, K;
};

__global__ __launch_bounds__(256) void k_gemm5(GArgs ga) {
  __shared__ _Float16 As[2][64 * 64];    // 2 x 8 KB double buffer
  const int nrow = (NN + 63) / 64;       // 782
  int side = blockIdx.x >= nrow;
  int bid = side ? blockIdx.x - nrow : blockIdx.x;
  const _Float16* A = side ? ga.A1 : ga.A0;
  const _Float16* Wt = side ? ga.Wt1 : ga.Wt0;
  _Float16* Z = side ? ga.Z1 : ga.Z0;
  const float* al = side ? ga.al1 : ga.al0;
  float* EL = side ? ga.EL1 : ga.EL0;
  const int K = ga.K, M = ga.M;
  int row0 = bid * 64;
  int wave = threadIdx.x >> 6;           // wave == head; cols wave*64..
  int lane = threadIdx.x & 63;
  int lr = lane & 15, kg = lane >> 4;
  int col0 = wave * 64;

  // stage A tile [row0..row0+64) x [k0..k0+64) into As[buf]; source pre-swizzled
  auto stage = [&](int buf, int k0) {
#pragma unroll
    for (int j = 0; j < 2; ++j) {
      int Lb = j * 4096 + wave * 1024;          // wave-uniform LDS byte base
      int L = Lb + lane * 16;                   // this lane's linear slot
      int r = L >> 7;                           // row in tile (128B per row)
      int kb = (L & 127) ^ ((r & 7) << 4);      // pre-swizzled source column byte
      int rg = row0 + r; rg = rg < M ? rg : M - 1;
      const char* gsrc = (const char*)A + ((size_t)rg * K + k0) * 2 + kb;
      char* ldst = (char*)(&As[buf][0]) + Lb;
      __builtin_amdgcn_global_load_lds(
          (const __attribute__((address_space(1))) unsigned int*)gsrc,
          (__attribute__((address_space(3))) unsigned int*)ldst, 16, 0, 0);
    }
  };

  f32x4 acc[4][4];
#pragma unroll
  for (int i = 0; i < 4; ++i)
#pragma unroll
    for (int j = 0; j < 4; ++j) acc[i][j] = (f32x4){0.f, 0.f, 0.f, 0.f};

  int nt = K >> 6;   // BK = 64
  stage(0, 0);
  __syncthreads();
  for (int t = 0; t < nt; ++t) {
    if (t + 1 < nt) stage((t + 1) & 1, (t + 1) * 64);
    const char* abuf = (const char*)(&As[t & 1][0]);
#pragma unroll
    for (int s = 0; s < 2; ++s) {
      int kk = t * 64 + s * 32 + kg * 8;
      f16x8 af[4], bfr[4];
#pragma unroll
      for (int mt = 0; mt < 4; ++mt) {
        int r = mt * 16 + lr;
        int cb = ((s << 6) | (kg << 4)) ^ ((r & 7) << 4);   // swizzled read
        af[mt] = *reinterpret_cast<const f16x8*>(abuf + r * 128 + cb);
      }
#pragma unroll
      for (int ct = 0; ct < 4; ++ct) {
        int c = col0 + ct * 16 + lr;
        bfr[ct] = *reinterpret_cast<const f16x8*>(Wt + (size_t)c * K + kk);
      }
#pragma unroll
      for (int mt = 0; mt < 4; ++mt)
#pragma unroll
        for (int ct = 0; ct < 4; ++ct)
          acc[mt][ct] = __builtin_amdgcn_mfma_f32_16x16x32_f16(af[mt], bfr[ct], acc[mt][ct], 0, 0, 0);
    }
    __syncthreads();
  }

  // C-write: col = lane&15, row = (lane>>4)*4 + reg
#pragma unroll
  for (int mt = 0; mt < 4; ++mt) {
#pragma unroll
    for (int r = 0; r < 4; ++r) {
      int row = row0 + mt * 16 + kg * 4 + r;
      if (row < M) {
#pragma unroll
        for (int ct = 0; ct < 4; ++ct) {
          int col = col0 + ct * 16 + lr;
          Z[(size_t)row * HF + col] = (_Float16)acc[mt][ct][r];
        }
      }
    }
  }
  // fused el epilogue: this wave's 64 cols == head(=wave)'s 64 dims
  float al4[4];
#pragma unroll
  for (int ct = 0; ct < 4; ++ct) al4[ct] = al[col0 + ct * 16 + lr];
#pragma unroll
  for (int mt = 0; mt < 4; ++mt) {
#pragma unroll
    for (int r = 0; r < 4; ++r) {
      float p = acc[mt][0][r] * al4[0] + acc[mt][1][r] * al4[1] +
                acc[mt][2][r] * al4[2] + acc[mt][3][r] * al4[3];
#pragma unroll
      for (int off = 1; off < 16; off <<= 1) p += __shfl_xor(p, off);
      int row = row0 + mt * 16 + kg * 4 + r;
      if (lr == 0 && row < M) EL[(size_t)row * 4 + wave] = p;
    }
  }
}

// ---------- CSR build (both relations per dispatch) ----------
__global__ __launch_bounds__(256) void k_hist2(const int* __restrict__ d0, const int* __restrict__ d1,
                                               int* __restrict__ c0, int* __restrict__ c1) {
  int t = blockIdx.x * 256 + threadIdx.x;
  if (t < NE) atomicAdd(&c0[d0[t]], 1);
  else if (t < 2 * NE) atomicAdd(&c1[d1[t - NE]], 1);
}

__global__ __launch_bounds__(1024) void k_scan1_2(const int* __restrict__ c0, const int* __restrict__ c1,
                                                  int* __restrict__ rp0, int* __restrict__ rp1,
                                                  int* __restrict__ b0, int* __restrict__ b1, int nscan) {
  __shared__ int tmp[1024];
  int rel = blockIdx.x >= nscan;
  int blk = rel ? blockIdx.x - nscan : blockIdx.x;
  const int* counts = rel ? c1 : c0;
  int* rp = rel ? rp1 : rp0;
  int* bsum = rel ? b1 : b0;
  int i = blk * 1024 + threadIdx.x;
  int v = (i < NN) ? counts[i] : 0;
  tmp[threadIdx.x] = v;
  __syncthreads();
  for (int off = 1; off < 1024; off <<= 1) {
    int t = (threadIdx.x >= off) ? tmp[threadIdx.x - off] : 0;
    __syncthreads();
    tmp[threadIdx.x] += t;
    __syncthreads();
  }
  if (i < NN) rp[i] = tmp[threadIdx.x] - v;  // block-local exclusive
  if (threadIdx.x == 1023) bsum[blk] = tmp[1023];
}

__global__ __launch_bounds__(128) void k_scan2_2(int* __restrict__ b0, int* __restrict__ b1, int nb) {
  int rel = threadIdx.x >> 6;
  int l = threadIdx.x & 63;
  int* bsum = rel ? b1 : b0;
  int orig = (l < nb) ? bsum[l] : 0;
  int v = orig;
#pragma unroll
  for (int off = 1; off < 64; off <<= 1) {
    int t = __shfl_up(v, off);
    if (l >= off) v += t;
  }
  if (l < nb) bsum[l] = v - orig;  // exclusive
}

__global__ __launch_bounds__(1024) void k_scan3_2(int* __restrict__ rp0, int* __restrict__ rp1,
                                                  const int* __restrict__ b0, const int* __restrict__ b1,
                                                  int nscan) {
  int rel = blockIdx.x >= nscan;
  int blk = rel ? blockIdx.x - nscan : blockIdx.x;
  int* rp = rel ? rp1 : rp0;
  const int* bsum = rel ? b1 : b0;
  int i = blk * 1024 + threadIdx.x;
  if (i < NN) rp[i] += bsum[blk];
  if (i == 0) rp[NN] = NE;
}

__global__ __launch_bounds__(256) void k_scatter2(
    const int* __restrict__ s0, const int* __restrict__ d0,
    const int* __restrict__ s1, const int* __restrict__ d1,
    const int* __restrict__ rp0, const int* __restrict__ rp1,
    int* __restrict__ f0, int* __restrict__ f1,
    int* __restrict__ cs0, int* __restrict__ cs1) {
  int t = blockIdx.x * 256 + threadIdx.x;
  if (t < NE) {
    int d = d0[t];
    int pos = rp0[d] + atomicAdd(&f0[d], 1);
    cs0[pos] = s0[t];
  } else if (t < 2 * NE) {
    int e = t - NE;
    int d = d1[e];
    int pos = rp1[d] + atomicAdd(&f1[d], 1);
    cs1[pos] = s1[e];
  }
}

__device__ __forceinline__ float pick_h(float4 v, int h) {
  float r = v.x;
  r = (h == 1) ? v.y : r;
  r = (h == 2) ? v.z : r;
  r = (h == 3) ? v.w : r;
  return r;
}

// ---------- fused GAT aggregation, both relations per dispatch ----------
template <typename OT>
__global__ __launch_bounds__(256) void k_agg2(
    const int* __restrict__ rpA, const int* __restrict__ csA,
    const float* __restrict__ elA, const float* __restrict__ erA,
    const _Float16* __restrict__ ZA, const float* __restrict__ bA, OT* __restrict__ oA,
    const int* __restrict__ rpB, const int* __restrict__ csB,
    const float* __restrict__ elB, const float* __restrict__ erB,
    const _Float16* __restrict__ ZB, const float* __restrict__ bB, OT* __restrict__ oB) {
  __shared__ float exs[4][256];
  __shared__ int ssrc[4][64];
  int nb = (NN + 3) / 4;
  int rel = blockIdx.x >= nb;
  int bid = rel ? blockIdx.x - nb : blockIdx.x;
  const int* rp = rel ? rpB : rpA;
  const int* csrc = rel ? csB : csA;
  const float* el = rel ? elB : elA;
  const float* er = rel ? erB : erA;
  const _Float16* Z = rel ? ZB : ZA;
  const float* bias = rel ? bB : bA;
  OT* out = rel ? oB : oA;

  int wv = threadIdx.x >> 6;
  int wid = bid * 4 + wv;
  if (wid >= NN) return;
  int lane = threadIdx.x & 63;
  int half = lane >> 5, l5 = lane & 31;
  int c0 = l5 * 8;      // 8 cols per lane (halves cover full row)
  int h = l5 >> 3;      // head for cols c0..c0+7
  int beg = rp[wid], end = rp[wid + 1];
  int deg = end - beg;

  if (deg == 0) {
    if (half == 0) {
      float4 b0 = *reinterpret_cast<const float4*>(bias + c0);
      float4 b1 = *reinterpret_cast<const float4*>(bias + c0 + 4);
      if constexpr (std::is_same<OT, float>::value) {
        float4* op = reinterpret_cast<float4*>(out + (size_t)wid * HF + c0);
        op[0] = b0; op[1] = b1;
      } else {
        f16x8 o = {(_Float16)b0.x, (_Float16)b0.y, (_Float16)b0.z, (_Float16)b0.w,
                   (_Float16)b1.x, (_Float16)b1.y, (_Float16)b1.z, (_Float16)b1.w};
        *reinterpret_cast<f16x8*>(out + (size_t)wid * HF + c0) = o;
      }
    }
    return;
  }

  if (deg <= 64) {
    // ---- pass A: lane i owns edge i ----
    int s = 0;
    float4 x = {-1e30f, -1e30f, -1e30f, -1e30f};
    float4 b = *reinterpret_cast<const float4*>(er + (size_t)wid * 4);
    if (lane < deg) {
      s = csrc[beg + lane];
      float4 a = reinterpret_cast<const float4*>(el)[s];
      x.x = a.x + b.x; x.x = x.x >= 0.f ? x.x : 0.2f * x.x;
      x.y = a.y + b.y; x.y = x.y >= 0.f ? x.y : 0.2f * x.y;
      x.z = a.z + b.z; x.z = x.z >= 0.f ? x.z : 0.2f * x.z;
      x.w = a.w + b.w; x.w = x.w >= 0.f ? x.w : 0.2f * x.w;
    }
    float4 m = x;
#pragma unroll
    for (int off = 32; off > 0; off >>= 1) {
      m.x = fmaxf(m.x, __shfl_xor(m.x, off));
      m.y = fmaxf(m.y, __shfl_xor(m.y, off));
      m.z = fmaxf(m.z, __shfl_xor(m.z, off));
      m.w = fmaxf(m.w, __shfl_xor(m.w, off));
    }
    float4 ex = {0.f, 0.f, 0.f, 0.f};
    if (lane < deg) {
      ex.x = __expf(x.x - m.x);
      ex.y = __expf(x.y - m.y);
      ex.z = __expf(x.z - m.z);
      ex.w = __expf(x.w - m.w);
    }
    float4 sm = ex;
#pragma unroll
    for (int off = 32; off > 0; off >>= 1) {
      sm.x += __shfl_xor(sm.x, off);
      sm.y += __shfl_xor(sm.y, off);
      sm.z += __shfl_xor(sm.z, off);
      sm.w += __shfl_xor(sm.w, off);
    }
    float inv = 1.0f / pick_h(sm, h);
    if (lane < deg) {
      *reinterpret_cast<float4*>(&exs[wv][lane * 4]) = ex;
      ssrc[wv][lane] = s;
    }
    // ---- pass B: halves own alternate edges, 4-group unroll -> 8 gathers in flight ----
    float a8[8] = {0.f, 0.f, 0.f, 0.f, 0.f, 0.f, 0.f, 0.f};
    int j = half;
#define AGG_STEP(J)                                                        \
    {                                                                      \
      int sj = ssrc[wv][(J)];                                              \
      float wj = exs[wv][(J) * 4 + h];                                     \
      f16x8 z = *reinterpret_cast<const f16x8*>(Z + (size_t)sj * HF + c0); \
      _Pragma("unroll")                                                    \
      for (int q = 0; q < 8; ++q) a8[q] += wj * (float)z[q];               \
    }
    for (; j + 6 < deg; j += 8) {
      AGG_STEP(j); AGG_STEP(j + 2); AGG_STEP(j + 4); AGG_STEP(j + 6);
    }
    for (; j < deg; j += 2) { AGG_STEP(j); }
#undef AGG_STEP
#pragma unroll
    for (int q = 0; q < 8; ++q) a8[q] += __shfl_xor(a8[q], 32);
    if (half == 0) {
      float4 b0 = *reinterpret_cast<const float4*>(bias + c0);
      float4 b1 = *reinterpret_cast<const float4*>(bias + c0 + 4);
      float r0 = a8[0] * inv + b0.x, r1 = a8[1] * inv + b0.y;
      float r2 = a8[2] * inv + b0.z, r3 = a8[3] * inv + b0.w;
      float r4 = a8[4] * inv + b1.x, r5 = a8[5] * inv + b1.y;
      float r6 = a8[6] * inv + b1.z, r7 = a8[7] * inv + b1.w;
      if constexpr (std::is_same<OT, float>::value) {
        float4* op = reinterpret_cast<float4*>(out + (size_t)wid * HF + c0);
        op[0] = (float4){r0, r1, r2, r3};
        op[1] = (float4){r4, r5, r6, r7};
      } else {
        f16x8 o = {(_Float16)r0, (_Float16)r1, (_Float16)r2, (_Float16)r3,
                   (_Float16)r4, (_Float16)r5, (_Float16)r6, (_Float16)r7};
        *reinterpret_cast<f16x8*>(out + (size_t)wid * HF + c0) = o;
      }
    }
    return;
  }

  // ---- rare fallback (deg > 64): uniform two-pass, full-wave f16x4 mapping ----
  {
    int c4 = lane * 4;
    int h4 = lane >> 4;
    float4 b = *reinterpret_cast<const float4*>(er + (size_t)wid * 4);
    float4 m = {-1e30f, -1e30f, -1e30f, -1e30f};
    for (int e = beg; e < end; ++e) {
      int s = csrc[e];
      float4 a = reinterpret_cast<const float4*>(el)[s];
      float4 x;
      x.x = a.x + b.x; x.x = x.x >= 0.f ? x.x : 0.2f * x.x;
      x.y = a.y + b.y; x.y = x.y >= 0.f ? x.y : 0.2f * x.y;
      x.z = a.z + b.z; x.z = x.z >= 0.f ? x.z : 0.2f * x.z;
      x.w = a.w + b.w; x.w = x.w >= 0.f ? x.w : 0.2f * x.w;
      m.x = fmaxf(m.x, x.x); m.y = fmaxf(m.y, x.y);
      m.z = fmaxf(m.z, x.z); m.w = fmaxf(m.w, x.w);
    }
    float4 sm = {0.f, 0.f, 0.f, 0.f};
    float4 acc = {0.f, 0.f, 0.f, 0.f};
    for (int e = beg; e < end; ++e) {
      int s = csrc[e];
      float4 a = reinterpret_cast<const float4*>(el)[s];
      float4 x;
      x.x = a.x + b.x; x.x = x.x >= 0.f ? x.x : 0.2f * x.x;
      x.y = a.y + b.y; x.y = x.y >= 0.f ? x.y : 0.2f * x.y;
      x.z = a.z + b.z; x.z = x.z >= 0.f ? x.z : 0.2f * x.z;
      x.w = a.w + b.w; x.w = x.w >= 0.f ? x.w : 0.2f * x.w;
      float4 exv;
      exv.x = __expf(x.x - m.x); exv.y = __expf(x.y - m.y);
      exv.z = __expf(x.z - m.z); exv.w = __expf(x.w - m.w);
      sm.x += exv.x; sm.y += exv.y; sm.z += exv.z; sm.w += exv.w;
      float w0 = pick_h(exv, h4);
      f16x4 z0 = *reinterpret_cast<const f16x4*>(Z + (size_t)s * HF + c4);
      acc.x += w0 * (float)z0.x;
      acc.y += w0 * (float)z0.y;
      acc.z += w0 * (float)z0.z;
      acc.w += w0 * (float)z0.w;
    }
    float inv = 1.0f / pick_h(sm, h4);
    float4 bv = *reinterpret_cast<const float4*>(bias + c4);
    float r0 = acc.x * inv + bv.x, r1 = acc.y * inv + bv.y;
    float r2 = acc.z * inv + bv.z, r3 = acc.w * inv + bv.w;
    if constexpr (std::is_same<OT, float>::value) {
      *reinterpret_cast<float4*>(out + (size_t)wid * HF + c4) = (float4){r0, r1, r2, r3};
    } else {
      f16x4 o = {(_Float16)r0, (_Float16)r1, (_Float16)r2, (_Float16)r3};
      *reinterpret_cast<f16x4*>(out + (size_t)wid * HF + c4) = o;
    }
  }
}

// ---------- batchnorm stats, both sides per dispatch ----------
__global__ __launch_bounds__(256) void k_bn_stats2(const _Float16* __restrict__ XU,
                                                   const _Float16* __restrict__ XI,
                                                   float* __restrict__ su, float* __restrict__ qu,
                                                   float* __restrict__ si, float* __restrict__ qi) {
  int rel = blockIdx.x >> 9;  // grid = 1024
  int blk = blockIdx.x & 511;
  const _Float16* X = rel ? XI : XU;
  float* sums = rel ? si : su;
  float* sqs = rel ? qi : qu;
  int c = threadIdx.x;
  float s = 0.f, q = 0.f;
  for (int r = blk; r < NN; r += 512) {
    float v = (float)X[(size_t)r * HF + c];
    s += v;
    q += v * v;
  }
  atomicAdd(&sums[c], s);
  atomicAdd(&sqs[c], q);
}

// ---------- batchnorm apply, both sides per dispatch (RAW16 -> H16) ----------
__global__ __launch_bounds__(256) void k_bn_apply2(
    const _Float16* __restrict__ XU, const _Float16* __restrict__ XI,
    const float* __restrict__ su, const float* __restrict__ qu,
    const float* __restrict__ si, const float* __restrict__ qi,
    const float* __restrict__ gU, const float* __restrict__ btU,
    const float* __restrict__ gI, const float* __restrict__ btI,
    _Float16* __restrict__ YU, _Float16* __restrict__ YI, int act) {
  const int nb = NN * HF / 8 / 256;  // 6250
  int rel = blockIdx.x >= nb;
  int bid = rel ? blockIdx.x - nb : blockIdx.x;
  const _Float16* X = rel ? XI : XU;
  const float* sums = rel ? si : su;
  const float* sqs = rel ? qi : qu;
  const float* g = rel ? gI : gU;
  const float* bt = rel ? btI : btU;
  _Float16* Y = rel ? YI : YU;
  int gid = bid * 256 + threadIdx.x;
  int i0 = gid * 8;
  int c0 = i0 & 255;
  const float invN = 1.0f / NN;
  f16x8 xv = *reinterpret_cast<const f16x8*>(X + i0);
  float4 s0 = *reinterpret_cast<const float4*>(sums + c0);
  float4 s1 = *reinterpret_cast<const float4*>(sums + c0 + 4);
  float4 q0 = *reinterpret_cast<const float4*>(sqs + c0);
  float4 q1 = *reinterpret_cast<const float4*>(sqs + c0 + 4);
  float4 g0 = *reinterpret_cast<const float4*>(g + c0);
  float4 g1 = *reinterpret_cast<const float4*>(g + c0 + 4);
  float4 b0 = *reinterpret_cast<const float4*>(bt + c0);
  float4 b1 = *reinterpret_cast<const float4*>(bt + c0 + 4);
  float sa[8] = {s0.x, s0.y, s0.z, s0.w, s1.x, s1.y, s1.z, s1.w};
  float qa[8] = {q0.x, q0.y, q0.z, q0.w, q1.x, q1.y, q1.z, q1.w};
  float ga[8] = {g0.x, g0.y, g0.z, g0.w, g1.x, g1.y, g1.z, g1.w};
  float ba[8] = {b0.x, b0.y, b0.z, b0.w, b1.x, b1.y, b1.z, b1.w};
  f16x8 o;
#pragma unroll
  for (int j = 0; j < 8; ++j) {
    float mu = sa[j] * invN;
    float var = qa[j] * invN - mu * mu;
    float sc = rsqrtf(var + 1e-5f) * ga[j];
    float v = ((float)xv[j] - mu) * sc + ba[j];
    v = act ? tanhf(v) : (v >= 0.f ? v : 0.01f * v);
    o[j] = (_Float16)v;
  }
  *reinterpret_cast<f16x8*>(Y + i0) = o;
}

extern "C" void kernel_launch(void* const* d_in, const int* in_sizes, int n_in,
                              void* d_out, int out_size, void* d_ws, size_t ws_size,
                              hipStream_t stream) {
  (void)in_sizes; (void)n_in; (void)out_size; (void)ws_size;
  const float* x_user = (const float*)d_in[0];
  const float* x_item = (const float*)d_in[1];
  const int* ui_src = (const int*)d_in[2];
  const int* ui_dst = (const int*)d_in[3];
  const int* iu_src = (const int*)d_in[4];
  const int* iu_dst = (const int*)d_in[5];
  const float *Wp[4], *alp[4], *arp[4], *bp[4];
  for (int l = 0; l < 4; ++l) {
    Wp[l]  = (const float*)d_in[6 + 4 * l];
    alp[l] = (const float*)d_in[7 + 4 * l];
    arp[l] = (const float*)d_in[8 + 4 * l];
    bp[l]  = (const float*)d_in[9 + 4 * l];
  }
  const float* bng = (const float*)d_in[22];
  const float* bnb = (const float*)d_in[23];

  char* w = (char*)d_ws;
  auto alloc = [&](size_t bytes) -> void* {
    void* p = (void*)w;
    w += (bytes + 255) & ~(size_t)255;
    return p;
  };
  _Float16* XU16 = (_Float16*)alloc((size_t)NN * 128 * 2);
  _Float16* XI16 = (_Float16*)alloc((size_t)NN * 128 * 2);
  _Float16* H16U = (_Float16*)alloc((size_t)NN * HF * 2);
  _Float16* H16I = (_Float16*)alloc((size_t)NN * HF * 2);
  _Float16* Z0 = (_Float16*)alloc((size_t)NN * HF * 2);
  _Float16* Z1 = (_Float16*)alloc((size_t)NN * HF * 2);
  _Float16* RAW16U = (_Float16*)alloc((size_t)NN * HF * 2);
  _Float16* RAW16I = (_Float16*)alloc((size_t)NN * HF * 2);
  float* EL0 = (float*)alloc((size_t)NN * 4 * 4);
  float* ER0 = (float*)alloc((size_t)NN * 4 * 4);
  float* EL1 = (float*)alloc((size_t)NN * 4 * 4);
  float* ER1 = (float*)alloc((size_t)NN * 4 * 4);
  _Float16* WT = (_Float16*)alloc((size_t)8 * 65536 * 2);
  float* ATTN = (float*)alloc((size_t)8 * 1024 * 4);   // [l*2+r][256][4]
  int* rp_ui = (int*)alloc((size_t)(NN + 1) * 4);
  int* rp_iu = (int*)alloc((size_t)(NN + 1) * 4);
  int* csrc_ui = (int*)alloc((size_t)NE * 4);
  int* csrc_iu = (int*)alloc((size_t)NE * 4);
  int* counts = (int*)alloc((size_t)4 * NN * 4);  // counts_ui | counts_iu | fill_ui | fill_iu
  int* bsum_ui = (int*)alloc((size_t)64 * 4);
  int* bsum_iu = (int*)alloc((size_t)64 * 4);
  float* stats = (float*)alloc((size_t)6 * 512 * 4);

  int* counts_ui = counts;
  int* counts_iu = counts + NN;
  int* fill_ui = counts + 2 * NN;
  int* fill_iu = counts + 3 * NN;

  hipMemsetAsync(counts, 0, (size_t)4 * NN * 4, stream);
  hipMemsetAsync(stats, 0, (size_t)6 * 512 * 4, stream);

  // input conversion (one dispatch)
  int n4 = NN * 128 / 4;
  k_tofp16_2<<<(2 * n4 + 255) / 256, 256, 0, stream>>>(x_user, x_item, XU16, XI16, n4);

  // all weight transposes (one dispatch)
  TArgs ta;
  int cum = 0;
  for (int l = 0; l < 4; ++l) {
    int K = (l == 0) ? 128 : 256;
    for (int r = 0; r < 2; ++r) {
      int s = l * 2 + r;
      ta.W[s] = Wp[l] + (size_t)r * K * HF;
      ta.dst[s] = WT + (size_t)s * 65536;
      ta.K[s] = K;
      ta.cum[s] = cum;
      cum += K * 256;
    }
  }
  ta.cum[8] = cum;
  k_transpose_all<<<(cum + 255) / 256, 256, 0, stream>>>(ta);

  // all W.ar attn tables (one dispatch)
  k_makeattn_all<<<(8 * 256 * 4 + 255) / 256, 256, 0, stream>>>(
      Wp[0], Wp[1], Wp[2], Wp[3], arp[0], arp[1], arp[2], arp[3], ATTN);

  // CSR build (both relations per dispatch)
  int egrid2 = (2 * NE + 255) / 256;
  int nscan = (NN + 1023) / 1024;
  k_hist2<<<egrid2, 256, 0, stream>>>(ui_dst, iu_dst, counts_ui, counts_iu);
  k_scan1_2<<<2 * nscan, 1024, 0, stream>>>(counts_ui, counts_iu, rp_ui, rp_iu, bsum_ui, bsum_iu, nscan);
  k_scan2_2<<<1, 128, 0, stream>>>(bsum_ui, bsum_iu, nscan);
  k_scan3_2<<<2 * nscan, 1024, 0, stream>>>(rp_ui, rp_iu, bsum_ui, bsum_iu, nscan);
  k_scatter2<<<egrid2, 256, 0, stream>>>(ui_src, ui_dst, iu_src, iu_dst, rp_ui, rp_iu,
                                         fill_ui, fill_iu, csrc_ui, csrc_iu);

  int agrid = (NN + 3) / 4;
  int nrow = (NN + 63) / 64;
  float* out_user = (float*)d_out;
  float* out_item = (float*)d_out + (size_t)NN * HF;

  for (int l = 0; l < 4; ++l) {
    int K = (l == 0) ? 128 : 256;
    const _Float16* Au = (l == 0) ? XU16 : H16U;
    const _Float16* Ai = (l == 0) ? XI16 : H16I;
    const float* war0 = ATTN + (size_t)(l * 2 + 0) * 1024;
    const float* war1 = ATTN + (size_t)(l * 2 + 1) * 1024;

    // er0 = hi . (W0.ar0), er1 = hu . (W1.ar1)   (one dispatch; A already post-BN)
    k_gemv_er2<<<2 * agrid, 256, 0, stream>>>(Ai, Au, war0, war1, ER0, ER1, K);

    // GEMM pair: Z0 = hu@W0 (+el0), Z1 = hi@W1 (+el1)
    GArgs ga;
    ga.A0 = Au; ga.A1 = Ai;
    ga.Wt0 = WT + (size_t)(l * 2 + 0) * 65536;
    ga.Wt1 = WT + (size_t)(l * 2 + 1) * 65536;
    ga.Z0 = Z0; ga.Z1 = Z1;
    ga.al0 = alp[l] + 0; ga.al1 = alp[l] + 256;
    ga.EL0 = EL0; ga.EL1 = EL1;
    ga.M = NN; ga.K = K;
    k_gemm5<<<2 * nrow, 256, 0, stream>>>(ga);

    // aggregation pair: u->i (dst items, Z0) and i->u (dst users, Z1)
    if (l < 3)
      k_agg2<_Float16><<<2 * agrid, 256, 0, stream>>>(
          rp_ui, csrc_ui, EL0, ER0, Z0, bp[l] + 0, RAW16I,
          rp_iu, csrc_iu, EL1, ER1, Z1, bp[l] + 256, RAW16U);
    else
      k_agg2<float><<<2 * agrid, 256, 0, stream>>>(
          rp_ui, csrc_ui, EL0, ER0, Z0, bp[l] + 0, out_item,
          rp_iu, csrc_iu, EL1, ER1, Z1, bp[l] + 256, out_user);

    if (l < 3) {
      int act = (l == 2) ? 1 : 0;
      float* su = stats + (size_t)(l * 2 + 0) * 512;
      float* si = stats + (size_t)(l * 2 + 1) * 512;
      k_bn_stats2<<<1024, 256, 0, stream>>>(RAW16U, RAW16I, su, su + 256, si, si + 256);
      k_bn_apply2<<<2 * (NN * HF / 8 / 256), 256, 0, stream>>>(
          RAW16U, RAW16I, su, su + 256, si, si + 256,
          bng + (size_t)(l * 2 + 0) * 256, bnb + (size_t)(l * 2 + 0) * 256,
          bng + (size_t)(l * 2 + 1) * 256, bnb + (size_t)(l * 2 + 1) * 256,
          H16U, H16I, act);
    }
  }
}